// Round 2
// baseline (685.749 us; speedup 1.0000x reference)
//
#include <hip/hip_runtime.h>
#include <stdint.h>
#include <math.h>

typedef __attribute__((ext_vector_type(8))) short short8;
typedef __attribute__((ext_vector_type(4))) float fx4;
typedef unsigned int u32;

#define MFMA16(a, b, c) __builtin_amdgcn_mfma_f32_16x16x32_bf16(a, b, c, 0, 0, 0)
#define SCL 0.04508422002777948f  // log2(e)/sqrt(1024)

#define CFENCE asm volatile("" ::: "memory")

// fp32 -> bf16 (RTNE), raw bits
__device__ __forceinline__ unsigned short f2bfu(float f) {
  unsigned u = __builtin_bit_cast(unsigned, f);
  u += 0x7fffu + ((u >> 16) & 1u);
  return (unsigned short)(u >> 16);
}

// raw v_exp_f32 (2^x), no ocml guard path
__device__ __forceinline__ float fast_exp2(float x) {
  float r;
  asm("v_exp_f32 %0, %1" : "=v"(r) : "v"(x));
  return r;
}

// async global->LDS, 16B per lane (dest = wave-uniform base + lane*16)
__device__ __forceinline__ void gl_lds16(const void* g, void* l) {
  __builtin_amdgcn_global_load_lds(
      (const __attribute__((address_space(1))) u32*)g,
      (__attribute__((address_space(3))) u32*)l, 16, 0, 0);
}

__device__ __forceinline__ void barx() {
  CFENCE;
  __builtin_amdgcn_s_barrier();
  CFENCE;
}

// ---------------------------------------------------------------------------
// prep: x [B,N,D] fp32 -> xbf [B,N,D] bf16 AND xT [B,D,N] bf16
// ---------------------------------------------------------------------------
__global__ __launch_bounds__(256) void prep_kernel(const float* __restrict__ x,
                                                   unsigned short* __restrict__ xT,
                                                   unsigned short* __restrict__ xbf) {
  __shared__ float tile[64 * 65];
  const int b = blockIdx.z, n0 = blockIdx.x * 64, d0 = blockIdx.y * 64;
  const int tid = threadIdx.x;
  const float* xb = x + ((size_t)b * 4096 + n0) * 1024 + d0;
#pragma unroll
  for (int i = 0; i < 4; i++) {
    int idx = tid + 256 * i;
    int r = idx >> 4, c4 = (idx & 15) * 4;
    const float4 v = *(const float4*)(xb + (size_t)r * 1024 + c4);
    float* tp = &tile[r * 65 + c4];
    tp[0] = v.x; tp[1] = v.y; tp[2] = v.z; tp[3] = v.w;
    uint2 pkt;
    pkt.x = (u32)f2bfu(v.x) | ((u32)f2bfu(v.y) << 16);
    pkt.y = (u32)f2bfu(v.z) | ((u32)f2bfu(v.w) << 16);
    *(uint2*)(xbf + ((size_t)b * 4096 + n0 + r) * 1024 + d0 + c4) = pkt;
  }
  __syncthreads();
  unsigned short* xo = xT + ((size_t)b * 1024 + d0) * 4096 + n0;
#pragma unroll
  for (int i = 0; i < 4; i++) {
    int idx = tid + 256 * i;
    int dr = idx >> 4, n4 = (idx & 15) * 4;
    unsigned short h0 = f2bfu(tile[(n4 + 0) * 65 + dr]);
    unsigned short h1 = f2bfu(tile[(n4 + 1) * 65 + dr]);
    unsigned short h2 = f2bfu(tile[(n4 + 2) * 65 + dr]);
    unsigned short h3 = f2bfu(tile[(n4 + 3) * 65 + dr]);
    uint2 pkt;
    pkt.x = (u32)h0 | ((u32)h1 << 16);
    pkt.y = (u32)h2 | ((u32)h3 << 16);
    *(uint2*)(xo + (size_t)dr * 4096 + n4) = pkt;
  }
}

// ---------------------------------------------------------------------------
// wconv: Wq,Wk fp32 [1024,1024] -> bf16
// ---------------------------------------------------------------------------
__global__ __launch_bounds__(256) void wconv_kernel(const float* __restrict__ Wq,
                                                    const float* __restrict__ Wk,
                                                    unsigned short* __restrict__ Wqb,
                                                    unsigned short* __restrict__ Wkb) {
  int gid = blockIdx.x * 256 + threadIdx.x;
  const float* s = (gid < 262144) ? Wq : Wk;
  unsigned short* d = (gid < 262144) ? Wqb : Wkb;
  int off = (gid & 262143) * 4;
  const float4 v = *(const float4*)(s + off);
  uint2 pkt;
  pkt.x = (u32)f2bfu(v.x) | ((u32)f2bfu(v.y) << 16);
  pkt.y = (u32)f2bfu(v.z) | ((u32)f2bfu(v.w) << 16);
  *(uint2*)(d + off) = pkt;
}

// ===========================================================================
// 8-phase 256-wide GEMM machinery. BK=64, 512 threads (8 waves).
// LDS per half-tile: [128 rows][64 shorts]; slot s: row=s>>3, oct=(s&7)^(row&7),
// LDS byte = halfbase + s*16 (linear, global_load_lds).
// Read (rel row ra, k-step st, quad q): byte = ra*128 + (((st*4+q)^(ra&7))*16).
// Stage plan per K-tile t (buffers alternate t&1):
//   P1: Ah1(t+1)->nbuf   P2: Bh1(t+1)->nbuf   P3: Bh0(t+2)->cbuf
//   P4: Ah0(t+2)->cbuf, then counted vmcnt, barrier.
// ===========================================================================

// ---------------------------------------------------------------------------
// core for BM=256, BN=128: waves 4M x 2N (wave tile 64x64, 4x4 frags).
// A-halves: 2 loads/thread, B-halves: 1. vmcnt steady state = 3.
// ONES: 0 = none; 2 = rowsum via ones-MFMA in wn==0 waves only, shared via
// LDS at the end (wn0/wn1 accl are identical by construction).
// ---------------------------------------------------------------------------
template <int ONES, int NT, int LDA, int LDB>
__device__ __forceinline__ void core128(const unsigned short* __restrict__ Ab,
                                        const unsigned short* __restrict__ Bb,
                                        short* lds, fx4 (&acc)[4][4], fx4 (&accl)[4]) {
  constexpr int BUFB = 49152;  // bytes per buffer: A 32K + B 16K
  const int tid = threadIdx.x;
  const int wave = tid >> 6, lane = tid & 63;
  const int wm = wave >> 1, wn = wave & 1;
  const int quad = lane >> 4, l16 = lane & 15;
  char* lp = (char*)lds;

  const int sr0 = tid >> 3, so0 = (tid & 7) ^ (sr0 & 7);
  const int ga0 = sr0 * LDA + so0 * 8;
  const int ga1 = ga0 + 64 * LDA;
  const int gb0 = sr0 * LDB + so0 * 8;
  const int ld0 = tid * 16;

  const int cst0 = (quad ^ (l16 & 7)) * 16;
  const int cst1 = ((4 + quad) ^ (l16 & 7)) * 16;
  const int arb = (wm >> 1) * 16384 + (wm & 1) * 8192 + l16 * 128;
  const int brb = 32768 + wn * 8192 + l16 * 128;

  short8 ones;
#pragma unroll
  for (int i = 0; i < 8; i++) ones[i] = (short)0x3F80;
#pragma unroll
  for (int i = 0; i < 4; i++) {
    accl[i] = (fx4)0.f;
#pragma unroll
    for (int j = 0; j < 4; j++) acc[i][j] = (fx4)0.f;
  }

#define PV_STGA(halfb, rowadd, bufb, kte)                                          \
  do {                                                                             \
    gl_lds16(Ab + (size_t)(rowadd) * LDA + (kte) + ga0, lp + (bufb) + (halfb) + ld0); \
    gl_lds16(Ab + (size_t)(rowadd) * LDA + (kte) + ga1,                            \
             lp + (bufb) + (halfb) + ld0 + 8192);                                  \
  } while (0)
#define PV_STGB(halfb, rowadd, bufb, kte) \
  gl_lds16(Bb + (size_t)(rowadd) * LDB + (kte) + gb0, lp + (bufb) + 32768 + (halfb) + ld0)

  // prologue
  PV_STGB(0, 0, 0, 0);
  PV_STGA(0, 0, 0, 0);
  PV_STGA(16384, 128, 0, 0);
  PV_STGB(8192, 64, 0, 0);
  PV_STGB(0, 0, BUFB, 64);
  PV_STGA(0, 0, BUFB, 64);
  asm volatile("s_waitcnt vmcnt(3)" ::: "memory");
  barx();

  short8 af[4], bf0[4], bf1[4];
  for (int t = 0; t < NT; ++t) {
    const int cbo = (t & 1) * BUFB, nbo = cbo ^ BUFB;
    const int kt1 = ((t + 1) & (NT - 1)) * 64;
    const int kt2 = ((t + 2) & (NT - 1)) * 64;
    // ---- phase 1: A mh0 + B nh0, stage Ah1(t+1)
#pragma unroll
    for (int mt = 0; mt < 2; mt++) {
      af[2 * mt] = *(const short8*)(lp + cbo + arb + mt * 2048 + cst0);
      af[2 * mt + 1] = *(const short8*)(lp + cbo + arb + mt * 2048 + cst1);
    }
#pragma unroll
    for (int nt = 0; nt < 2; nt++) {
      bf0[2 * nt] = *(const short8*)(lp + cbo + brb + nt * 2048 + cst0);
      bf0[2 * nt + 1] = *(const short8*)(lp + cbo + brb + nt * 2048 + cst1);
    }
    PV_STGA(16384, 128, nbo, kt1);
    barx();
    __builtin_amdgcn_s_setprio(1);
#pragma unroll
    for (int mt = 0; mt < 2; mt++) {
#pragma unroll
      for (int nt = 0; nt < 2; nt++) {
        acc[mt][nt] = MFMA16(af[2 * mt], bf0[2 * nt], acc[mt][nt]);
        acc[mt][nt] = MFMA16(af[2 * mt + 1], bf0[2 * nt + 1], acc[mt][nt]);
      }
      if (ONES && wn == 0) {
        accl[mt] = MFMA16(af[2 * mt], ones, accl[mt]);
        accl[mt] = MFMA16(af[2 * mt + 1], ones, accl[mt]);
      }
    }
    __builtin_amdgcn_s_setprio(0);
    barx();
    // ---- phase 2: B nh1, stage Bh1(t+1)
#pragma unroll
    for (int nt = 0; nt < 2; nt++) {
      bf1[2 * nt] = *(const short8*)(lp + cbo + brb + (nt + 2) * 2048 + cst0);
      bf1[2 * nt + 1] = *(const short8*)(lp + cbo + brb + (nt + 2) * 2048 + cst1);
    }
    PV_STGB(8192, 64, nbo, kt1);
    barx();
    __builtin_amdgcn_s_setprio(1);
#pragma unroll
    for (int mt = 0; mt < 2; mt++)
#pragma unroll
      for (int nt = 0; nt < 2; nt++) {
        acc[mt][nt + 2] = MFMA16(af[2 * mt], bf1[2 * nt], acc[mt][nt + 2]);
        acc[mt][nt + 2] = MFMA16(af[2 * mt + 1], bf1[2 * nt + 1], acc[mt][nt + 2]);
      }
    __builtin_amdgcn_s_setprio(0);
    barx();
    // ---- phase 3: A mh1, stage Bh0(t+2)
#pragma unroll
    for (int mt = 0; mt < 2; mt++) {
      af[2 * mt] = *(const short8*)(lp + cbo + arb + (mt + 2) * 2048 + cst0);
      af[2 * mt + 1] = *(const short8*)(lp + cbo + arb + (mt + 2) * 2048 + cst1);
    }
    PV_STGB(0, 0, cbo, kt2);
    barx();
    __builtin_amdgcn_s_setprio(1);
#pragma unroll
    for (int mt = 0; mt < 2; mt++) {
#pragma unroll
      for (int nt = 0; nt < 2; nt++) {
        acc[mt + 2][nt + 2] = MFMA16(af[2 * mt], bf1[2 * nt], acc[mt + 2][nt + 2]);
        acc[mt + 2][nt + 2] = MFMA16(af[2 * mt + 1], bf1[2 * nt + 1], acc[mt + 2][nt + 2]);
      }
      if (ONES && wn == 0) {
        accl[mt + 2] = MFMA16(af[2 * mt], ones, accl[mt + 2]);
        accl[mt + 2] = MFMA16(af[2 * mt + 1], ones, accl[mt + 2]);
      }
    }
    __builtin_amdgcn_s_setprio(0);
    barx();
    // ---- phase 4: stage Ah0(t+2), counted vmcnt, MFMA mh1 x nh0 (bf0 kept)
    PV_STGA(0, 0, cbo, kt2);
    asm volatile("s_waitcnt vmcnt(3)" ::: "memory");
    barx();
    __builtin_amdgcn_s_setprio(1);
#pragma unroll
    for (int mt = 0; mt < 2; mt++)
#pragma unroll
      for (int nt = 0; nt < 2; nt++) {
        acc[mt + 2][nt] = MFMA16(af[2 * mt], bf0[2 * nt], acc[mt + 2][nt]);
        acc[mt + 2][nt] = MFMA16(af[2 * mt + 1], bf0[2 * nt + 1], acc[mt + 2][nt]);
      }
    __builtin_amdgcn_s_setprio(0);
    barx();
  }
#undef PV_STGA
#undef PV_STGB
  if (ONES == 2) {
    // share accl from wn==0 to wn==1 waves. Bytes [0,1K) of buf0: last writer
    // was t=NT-2's P3/P4 stage, vmcnt-completed at t=NT-1's P4; in-flight DMA
    // (t=NT-1 P3/P4) targets buf1 only -> safe to reuse after final barrier.
    float* lf = (float*)lds;
    if (wn == 0 && l16 == 0) {
#pragma unroll
      for (int mt = 0; mt < 4; mt++)
#pragma unroll
        for (int i = 0; i < 4; i++) lf[wm * 64 + mt * 16 + quad * 4 + i] = accl[mt][i];
    }
    barx();
    if (wn == 1) {
#pragma unroll
      for (int mt = 0; mt < 4; mt++)
#pragma unroll
        for (int i = 0; i < 4; i++) accl[mt][i] = lf[wm * 64 + mt * 16 + quad * 4 + i];
    }
  }
}

// ---------------------------------------------------------------------------
// proj: Q/K = xbf @ Wbf^T (bf16). grid (64, 8, 2), block 512, XCD-swizzled
// ---------------------------------------------------------------------------
__global__ __launch_bounds__(512) void proj_kernel(
    const unsigned short* __restrict__ xbf, const unsigned short* __restrict__ Wqb,
    const unsigned short* __restrict__ Wkb, unsigned short* __restrict__ Qo,
    unsigned short* __restrict__ Ko) {
  __shared__ __attribute__((aligned(16))) short lds[49152];  // 96 KiB
  const int fid = blockIdx.x + 64 * (blockIdx.y + 8 * blockIdx.z);  // nwg=1024
  const int swz = (fid & 7) * 128 + (fid >> 3);
  const int bx = swz & 63, by = (swz >> 6) & 7, bzz = swz >> 9;
  const unsigned short* Wb = bzz ? Wkb : Wqb;
  unsigned short* O = bzz ? Ko : Qo;
  const int m0 = bx * 256, e0 = by * 128;
  fx4 acc[4][4], accl[4];
  core128<0, 16, 1024, 1024>(xbf + (size_t)m0 * 1024, Wb + (size_t)e0 * 1024, lds, acc, accl);
  const int wave = threadIdx.x >> 6, lane = threadIdx.x & 63;
  const int wm = wave >> 1, wn = wave & 1;
  const int quad = lane >> 4, l16 = lane & 15;
#pragma unroll
  for (int mt = 0; mt < 4; mt++) {
    const int row = m0 + wm * 64 + mt * 16 + quad * 4;
#pragma unroll
    for (int nt = 0; nt < 4; nt++) {
      const int col = e0 + wn * 64 + nt * 16 + l16;
      unsigned short* op = O + (size_t)row * 1024 + col;
#pragma unroll
      for (int i = 0; i < 4; i++) op[(size_t)i * 1024] = f2bfu(acc[mt][nt][i]);
    }
  }
}

// ---------------------------------------------------------------------------
// pv: O[b][q][d] = (P[bz] @ xT[b]^T) / (P[bz] @ 1), bf16 out.
// grid (16, 8, 2), block 512, K=4096, XCD-swizzled
// ---------------------------------------------------------------------------
__global__ __launch_bounds__(512) void pv_kernel(
    const unsigned short* __restrict__ P, const unsigned short* __restrict__ xT,
    unsigned short* __restrict__ Ost, int bbase) {
  __shared__ __attribute__((aligned(16))) short lds[49152];  // 96 KiB
  const int fid = blockIdx.x + 16 * (blockIdx.y + 8 * blockIdx.z);  // nwg=256
  const int swz = (fid & 7) * 32 + (fid >> 3);
  const int bx = swz & 15, by = (swz >> 4) & 7, bz = swz >> 7;
  const int b = bbase + bz;
  const int m0 = bx * 256, e0 = by * 128;
  const unsigned short* Ab = P + (size_t)bz * 4096 * 4096 + (size_t)m0 * 4096;
  const unsigned short* Bb = xT + (size_t)b * 1024 * 4096 + (size_t)e0 * 4096;
  fx4 acc[4][4], accl[4];
  core128<2, 64, 4096, 4096>(Ab, Bb, lds, acc, accl);
  unsigned short* O = Ost + (size_t)b * 4096 * 1024;
  const int wave = threadIdx.x >> 6, lane = threadIdx.x & 63;
  const int wm = wave >> 1, wn = wave & 1;
  const int quad = lane >> 4, l16 = lane & 15;
#pragma unroll
  for (int mt = 0; mt < 4; mt++) {
    const int row = m0 + wm * 64 + mt * 16 + quad * 4;
    const fx4 li = accl[mt];
    fx4 r;
#pragma unroll
    for (int i = 0; i < 4; i++) r[i] = __builtin_amdgcn_rcpf(li[i]);
#pragma unroll
    for (int nt = 0; nt < 4; nt++) {
      const int col = e0 + wn * 64 + nt * 16 + l16;
      unsigned short* op = O + (size_t)row * 1024 + col;
#pragma unroll
      for (int i = 0; i < 4; i++) op[(size_t)i * 1024] = f2bfu(acc[mt][nt][i] * r[i]);
    }
  }
}

// ---------------------------------------------------------------------------
// qk: P[bz][q][key] = exp2((Q[b] @ K[b]^T) * SCL) bf16.
// grid (16, 8, 2) XCD-swizzled, block 512, BM=256. Each block computes TWO
// 256-wide n-subtiles (n = by*512 + sub*256) with a CONTINUOUS pipeline:
// TT=32 tiles, B panel = Bp[tt>>4], kte = (tt&15)*64. Subtile-0 epilogue runs
// between tile 15's P4 barrier and tile 16's P1 (prefetches already in
// flight). waves 2M x 4N (wave tile 128x64), acc[8][4]. vmcnt steady = 4.
// ---------------------------------------------------------------------------
__global__ __launch_bounds__(512) void qk_kernel(
    const unsigned short* __restrict__ Qb, const unsigned short* __restrict__ Kb,
    unsigned short* __restrict__ Pp, int bbase) {
  __shared__ __attribute__((aligned(16))) short lds[65536];  // 128 KiB
  const int fid = blockIdx.x + 16 * (blockIdx.y + 8 * blockIdx.z);  // nwg=256
  const int swz = (fid & 7) * 32 + (fid >> 3);
  const int bx = swz & 15, by = (swz >> 4) & 7, bz = swz >> 7;
  const int b = bbase + bz;
  const unsigned short* A = Qb + (size_t)b * 4096 * 1024;
  const unsigned short* Bm = Kb + (size_t)b * 4096 * 1024;
  unsigned short* Pb = Pp + (size_t)bz * 4096 * 4096;
  const int m0 = bx * 256, nbase = by * 512;
  const int tid = threadIdx.x;
  const int wave = tid >> 6, lane = tid & 63;
  const int wm = wave >> 2, wn = wave & 3;
  const int quad = lane >> 4, l16 = lane & 15;
  char* lp = (char*)lds;

  const unsigned short* Ab = A + (size_t)m0 * 1024;
  const unsigned short* Bp[2] = {Bm + (size_t)nbase * 1024,
                                 Bm + (size_t)(nbase + 256) * 1024};
  const int sr0 = tid >> 3, so0 = (tid & 7) ^ (sr0 & 7);
  const int ga0 = sr0 * 1024 + so0 * 8;
  const int ga1 = ga0 + 64 * 1024;
  const int ld0 = tid * 16;

  const int cst0 = (quad ^ (l16 & 7)) * 16;
  const int cst1 = ((4 + quad) ^ (l16 & 7)) * 16;
  const int arb = wm * 16384 + l16 * 128;
  const int brb = 32768 + (wn >> 1) * 16384 + (wn & 1) * 8192 + l16 * 128;

  fx4 acc[8][4];
#pragma unroll
  for (int i = 0; i < 8; i++)
#pragma unroll
    for (int j = 0; j < 4; j++) acc[i][j] = (fx4)0.f;

#define QK_STG(OPb, halfb, rowadd, bufb, kte)                                       \
  do {                                                                              \
    gl_lds16(OPb + (size_t)(rowadd) * 1024 + (kte) + ga0, lp + (bufb) + (halfb) + ld0); \
    gl_lds16(OPb + (size_t)(rowadd) * 1024 + (kte) + ga1,                           \
             lp + (bufb) + (halfb) + ld0 + 8192);                                   \
  } while (0)

#define QK_EPI(sub)                                                              \
  do {                                                                           \
    _Pragma("unroll") for (int mt = 0; mt < 8; mt++) {                           \
      const int row = m0 + wm * 128 + mt * 16 + quad * 4;                        \
      _Pragma("unroll") for (int nt = 0; nt < 4; nt++) {                         \
        const int col = nbase + (sub)*256 + wn * 64 + nt * 16 + l16;             \
        unsigned short* pp = Pb + (size_t)row * 4096 + col;                      \
        _Pragma("unroll") for (int i = 0; i < 4; i++)                            \
            pp[(size_t)i * 4096] = f2bfu(fast_exp2(acc[mt][nt][i] * SCL));       \
        acc[mt][nt] = (fx4)0.f;                                                  \
      }                                                                          \
    }                                                                            \
  } while (0)

  // prologue: tiles 0,1 are both panel 0
  QK_STG(Bp[0], 32768, 0, 0, 0);
  QK_STG(Ab, 0, 0, 0, 0);
  QK_STG(Ab, 16384, 128, 0, 0);
  QK_STG(Bp[0], 49152, 128, 0, 0);
  QK_STG(Bp[0], 32768, 0, 65536, 64);
  QK_STG(Ab, 0, 0, 65536, 64);
  asm volatile("s_waitcnt vmcnt(4)" ::: "memory");
  barx();

  short8 af[8], bf0[4], bf1[4];
  for (int tt = 0; tt < 32; ++tt) {
    const int cbo = (tt & 1) * 65536, nbo = cbo ^ 65536;
    const int t1 = (tt + 1) & 31, t2 = (tt + 2) & 31;
    const int kt1 = (t1 & 15) * 64, kt2 = (t2 & 15) * 64;
    const unsigned short* B1 = Bp[t1 >> 4];
    const unsigned short* B2 = Bp[t2 >> 4];
    // ---- phase 1: A mh0 (mt 0..3) + B nh0 (nt 0..1), stage Ah1(t+1)
#pragma unroll
    for (int mt = 0; mt < 4; mt++) {
      af[2 * mt] = *(const short8*)(lp + cbo + arb + mt * 2048 + cst0);
      af[2 * mt + 1] = *(const short8*)(lp + cbo + arb + mt * 2048 + cst1);
    }
#pragma unroll
    for (int nt = 0; nt < 2; nt++) {
      bf0[2 * nt] = *(const short8*)(lp + cbo + brb + nt * 2048 + cst0);
      bf0[2 * nt + 1] = *(const short8*)(lp + cbo + brb + nt * 2048 + cst1);
    }
    QK_STG(Ab, 16384, 128, nbo, kt1);
    barx();
    __builtin_amdgcn_s_setprio(1);
#pragma unroll
    for (int mt = 0; mt < 4; mt++)
#pragma unroll
      for (int nt = 0; nt < 2; nt++) {
        acc[mt][nt] = MFMA16(af[2 * mt], bf0[2 * nt], acc[mt][nt]);
        acc[mt][nt] = MFMA16(af[2 * mt + 1], bf0[2 * nt + 1], acc[mt][nt]);
      }
    __builtin_amdgcn_s_setprio(0);
    barx();
    // ---- phase 2: B nh1 (nt 2..3), stage Bh1(t+1)
#pragma unroll
    for (int nt = 0; nt < 2; nt++) {
      bf1[2 * nt] = *(const short8*)(lp + cbo + brb + (nt + 2) * 2048 + cst0);
      bf1[2 * nt + 1] = *(const short8*)(lp + cbo + brb + (nt + 2) * 2048 + cst1);
    }
    QK_STG(B1, 49152, 128, nbo, kt1);
    barx();
    __builtin_amdgcn_s_setprio(1);
#pragma unroll
    for (int mt = 0; mt < 4; mt++)
#pragma unroll
      for (int nt = 0; nt < 2; nt++) {
        acc[mt][nt + 2] = MFMA16(af[2 * mt], bf1[2 * nt], acc[mt][nt + 2]);
        acc[mt][nt + 2] = MFMA16(af[2 * mt + 1], bf1[2 * nt + 1], acc[mt][nt + 2]);
      }
    __builtin_amdgcn_s_setprio(0);
    barx();
    // ---- phase 3: A mh1 (mt 4..7), stage Bh0(t+2)
#pragma unroll
    for (int mt = 0; mt < 4; mt++) {
      af[2 * mt] = *(const short8*)(lp + cbo + arb + (mt + 4) * 2048 + cst0);
      af[2 * mt + 1] = *(const short8*)(lp + cbo + arb + (mt + 4) * 2048 + cst1);
    }
    QK_STG(B2, 32768, 0, cbo, kt2);
    barx();
    __builtin_amdgcn_s_setprio(1);
#pragma unroll
    for (int mt = 0; mt < 4; mt++)
#pragma unroll
      for (int nt = 0; nt < 2; nt++) {
        acc[mt + 4][nt + 2] = MFMA16(af[2 * mt], bf1[2 * nt], acc[mt + 4][nt + 2]);
        acc[mt + 4][nt + 2] = MFMA16(af[2 * mt + 1], bf1[2 * nt + 1], acc[mt + 4][nt + 2]);
      }
    __builtin_amdgcn_s_setprio(0);
    barx();
    // ---- phase 4: stage Ah0(t+2), counted vmcnt, MFMA mh1 x nh0
    QK_STG(Ab, 0, 0, cbo, kt2);
    asm volatile("s_waitcnt vmcnt(4)" ::: "memory");
    barx();
    __builtin_amdgcn_s_setprio(1);
#pragma unroll
    for (int mt = 0; mt < 4; mt++)
#pragma unroll
      for (int nt = 0; nt < 2; nt++) {
        acc[mt + 4][nt] = MFMA16(af[2 * mt], bf0[2 * nt], acc[mt + 4][nt]);
        acc[mt + 4][nt] = MFMA16(af[2 * mt + 1], bf0[2 * nt + 1], acc[mt + 4][nt]);
      }
    __builtin_amdgcn_s_setprio(0);
    barx();
    if (tt == 15) {
      // subtile-0 epilogue; tiles 16,17 prefetches already in flight.
      QK_EPI(0);
    }
  }
  QK_EPI(1);
#undef QK_STG
#undef QK_EPI
}

// ---------------------------------------------------------------------------
// fin: O bf16 [B,N,D] -> d_out fp32
// ---------------------------------------------------------------------------
__global__ __launch_bounds__(256) void fin_kernel(const uint4* __restrict__ Ost,
                                                  float4* __restrict__ out) {
  size_t t = (size_t)blockIdx.x * 256 + threadIdx.x;
  const uint4 v = Ost[t];
  float4 o0, o1;
  o0.x = __builtin_bit_cast(float, v.x << 16);
  o0.y = __builtin_bit_cast(float, v.x & 0xffff0000u);
  o0.z = __builtin_bit_cast(float, v.y << 16);
  o0.w = __builtin_bit_cast(float, v.y & 0xffff0000u);
  o1.x = __builtin_bit_cast(float, v.z << 16);
  o1.y = __builtin_bit_cast(float, v.z & 0xffff0000u);
  o1.z = __builtin_bit_cast(float, v.w << 16);
  o1.w = __builtin_bit_cast(float, v.w & 0xffff0000u);
  out[t * 2] = o0;
  out[t * 2 + 1] = o1;
}

// ---------------------------------------------------------------------------
extern "C" void kernel_launch(void* const* d_in, const int* in_sizes, int n_in,
                              void* d_out, int out_size, void* d_ws, size_t ws_size,
                              hipStream_t stream) {
  const float* x = (const float*)d_in[0];
  const float* Wq = (const float*)d_in[1];
  const float* Wk = (const float*)d_in[2];
  char* ws = (char*)d_ws;
  // ws (96 MiB): xT bf16 @0 | Q bf16 @32Mi | K bf16 @64Mi
  // Q region reused as bf16 O staging once Q[b] is dead.
  unsigned short* xT = (unsigned short*)ws;
  unsigned short* Qb = (unsigned short*)(ws + (size_t)33554432);
  unsigned short* Kb = (unsigned short*)(ws + (size_t)67108864);
  unsigned short* Ost = Qb;
  // d_out as scratch until fin: phase A xbf/Wqb/Wkb; phase B P pair (64 MiB).
  unsigned short* xbf = (unsigned short*)d_out;
  unsigned short* Wqb = (unsigned short*)((char*)d_out + (size_t)33554432);
  unsigned short* Wkb = (unsigned short*)((char*)d_out + (size_t)35651584);
  unsigned short* Pp = (unsigned short*)d_out;

  hipLaunchKernelGGL(prep_kernel, dim3(64, 16, 4), dim3(256), 0, stream, x, xT, xbf);
  hipLaunchKernelGGL(wconv_kernel, dim3(2048), dim3(256), 0, stream, Wq, Wk, Wqb, Wkb);
  hipLaunchKernelGGL(proj_kernel, dim3(64, 8, 2), dim3(512), 0, stream, xbf, Wqb, Wkb, Qb, Kb);
  hipLaunchKernelGGL(qk_kernel, dim3(16, 8, 2), dim3(512), 0, stream, Qb, Kb, Pp, 0);
  hipLaunchKernelGGL(pv_kernel, dim3(16, 8, 2), dim3(512), 0, stream, Pp, xT, Ost, 0);
  hipLaunchKernelGGL(qk_kernel, dim3(16, 8, 2), dim3(512), 0, stream, Qb, Kb, Pp, 2);
  hipLaunchKernelGGL(pv_kernel, dim3(16, 8, 2), dim3(512), 0, stream, Pp, xT, Ost, 2);
  hipLaunchKernelGGL(fin_kernel, dim3(8192), dim3(256), 0, stream,
                     (const uint4*)Ost, (float4*)d_out);
}

// Round 3
// 497.098 us; speedup vs baseline: 1.3795x; 1.3795x over previous
//
#include <hip/hip_runtime.h>
#include <stdint.h>
#include <math.h>

typedef __attribute__((ext_vector_type(8))) short short8;
typedef __attribute__((ext_vector_type(4))) float fx4;
typedef unsigned int u32;

#define MFMA16(a, b, c) __builtin_amdgcn_mfma_f32_16x16x32_bf16(a, b, c, 0, 0, 0)
#define SCL 0.04508422002777948f  // log2(e)/sqrt(1024)

#define CFENCE asm volatile("" ::: "memory")

// fp32 -> bf16 (RTNE), raw bits
__device__ __forceinline__ unsigned short f2bfu(float f) {
  unsigned u = __builtin_bit_cast(unsigned, f);
  u += 0x7fffu + ((u >> 16) & 1u);
  return (unsigned short)(u >> 16);
}

// raw v_exp_f32 (2^x), no ocml guard path
__device__ __forceinline__ float fast_exp2(float x) {
  float r;
  asm("v_exp_f32 %0, %1" : "=v"(r) : "v"(x));
  return r;
}

// async global->LDS, 16B per lane (dest = wave-uniform base + lane*16)
__device__ __forceinline__ void gl_lds16(const void* g, void* l) {
  __builtin_amdgcn_global_load_lds(
      (const __attribute__((address_space(1))) u32*)g,
      (__attribute__((address_space(3))) u32*)l, 16, 0, 0);
}

__device__ __forceinline__ void barx() {
  CFENCE;
  __builtin_amdgcn_s_barrier();
  CFENCE;
}

// ---------------------------------------------------------------------------
// prep: x [B,N,D] fp32 -> xbf [B,N,D] bf16 AND xT [B,D,N] bf16
// ---------------------------------------------------------------------------
__global__ __launch_bounds__(256) void prep_kernel(const float* __restrict__ x,
                                                   unsigned short* __restrict__ xT,
                                                   unsigned short* __restrict__ xbf) {
  __shared__ float tile[64 * 65];
  const int b = blockIdx.z, n0 = blockIdx.x * 64, d0 = blockIdx.y * 64;
  const int tid = threadIdx.x;
  const float* xb = x + ((size_t)b * 4096 + n0) * 1024 + d0;
#pragma unroll
  for (int i = 0; i < 4; i++) {
    int idx = tid + 256 * i;
    int r = idx >> 4, c4 = (idx & 15) * 4;
    const float4 v = *(const float4*)(xb + (size_t)r * 1024 + c4);
    float* tp = &tile[r * 65 + c4];
    tp[0] = v.x; tp[1] = v.y; tp[2] = v.z; tp[3] = v.w;
    uint2 pkt;
    pkt.x = (u32)f2bfu(v.x) | ((u32)f2bfu(v.y) << 16);
    pkt.y = (u32)f2bfu(v.z) | ((u32)f2bfu(v.w) << 16);
    *(uint2*)(xbf + ((size_t)b * 4096 + n0 + r) * 1024 + d0 + c4) = pkt;
  }
  __syncthreads();
  unsigned short* xo = xT + ((size_t)b * 1024 + d0) * 4096 + n0;
#pragma unroll
  for (int i = 0; i < 4; i++) {
    int idx = tid + 256 * i;
    int dr = idx >> 4, n4 = (idx & 15) * 4;
    unsigned short h0 = f2bfu(tile[(n4 + 0) * 65 + dr]);
    unsigned short h1 = f2bfu(tile[(n4 + 1) * 65 + dr]);
    unsigned short h2 = f2bfu(tile[(n4 + 2) * 65 + dr]);
    unsigned short h3 = f2bfu(tile[(n4 + 3) * 65 + dr]);
    uint2 pkt;
    pkt.x = (u32)h0 | ((u32)h1 << 16);
    pkt.y = (u32)h2 | ((u32)h3 << 16);
    *(uint2*)(xo + (size_t)dr * 4096 + n4) = pkt;
  }
}

// ---------------------------------------------------------------------------
// wconv: Wq,Wk fp32 [1024,1024] -> bf16
// ---------------------------------------------------------------------------
__global__ __launch_bounds__(256) void wconv_kernel(const float* __restrict__ Wq,
                                                    const float* __restrict__ Wk,
                                                    unsigned short* __restrict__ Wqb,
                                                    unsigned short* __restrict__ Wkb) {
  int gid = blockIdx.x * 256 + threadIdx.x;
  const float* s = (gid < 262144) ? Wq : Wk;
  unsigned short* d = (gid < 262144) ? Wqb : Wkb;
  int off = (gid & 262143) * 4;
  const float4 v = *(const float4*)(s + off);
  uint2 pkt;
  pkt.x = (u32)f2bfu(v.x) | ((u32)f2bfu(v.y) << 16);
  pkt.y = (u32)f2bfu(v.z) | ((u32)f2bfu(v.w) << 16);
  *(uint2*)(d + off) = pkt;
}

// ===========================================================================
// 8-phase 256-wide GEMM machinery. BK=64, 512 threads (8 waves).
// LDS per half-tile: [128 rows][64 shorts]; slot s: row=s>>3, oct=(s&7)^(row&7),
// LDS byte = halfbase + s*16 (linear, global_load_lds).
// Read (rel row ra, k-step st, quad q): byte = ra*128 + (((st*4+q)^(ra&7))*16).
// Stage plan per K-tile t (buffers alternate t&1):
//   P1: Ah1(t+1)->nbuf   P2: Bh1(t+1)->nbuf   P3: Bh0(t+2)->cbuf
//   P4: Ah0(t+2)->cbuf, then counted vmcnt, barrier.
// WAR safety: each slot staged only after the phase barrier following its
// last read (A-halves last read P3, B-halves last read P2).
// RAW safety: vmcnt(N) at P4 leaves only the P3/P4 stages outstanding,
// forcing tile t+1 complete before its P1 reads.
// ===========================================================================

// ---------------------------------------------------------------------------
// core for BM=256, BN=128: waves 4M x 2N (wave tile 64x64, 4x4 frags).
// A-halves: 2 loads/thread, B-halves: 1. vmcnt steady state = 3.
// ---------------------------------------------------------------------------
template <int ONES, int NT, int LDA, int LDB>
__device__ __forceinline__ void core128(const unsigned short* __restrict__ Ab,
                                        const unsigned short* __restrict__ Bb,
                                        short* lds, fx4 (&acc)[4][4], fx4 (&accl)[4]) {
  constexpr int BUFB = 49152;  // bytes per buffer: A 32K + B 16K
  const int tid = threadIdx.x;
  const int wave = tid >> 6, lane = tid & 63;
  const int wm = wave >> 1, wn = wave & 1;
  const int quad = lane >> 4, l16 = lane & 15;
  char* lp = (char*)lds;

  const int sr0 = tid >> 3, so0 = (tid & 7) ^ (sr0 & 7);
  const int ga0 = sr0 * LDA + so0 * 8;
  const int ga1 = ga0 + 64 * LDA;
  const int gb0 = sr0 * LDB + so0 * 8;
  const int ld0 = tid * 16;

  const int cst0 = (quad ^ (l16 & 7)) * 16;
  const int cst1 = ((4 + quad) ^ (l16 & 7)) * 16;
  const int arb = (wm >> 1) * 16384 + (wm & 1) * 8192 + l16 * 128;
  const int brb = 32768 + wn * 8192 + l16 * 128;

  short8 ones;
#pragma unroll
  for (int i = 0; i < 8; i++) ones[i] = (short)0x3F80;
#pragma unroll
  for (int i = 0; i < 4; i++) {
    accl[i] = (fx4)0.f;
#pragma unroll
    for (int j = 0; j < 4; j++) acc[i][j] = (fx4)0.f;
  }

#define PV_STGA(halfb, rowadd, bufb, kte)                                          \
  do {                                                                             \
    gl_lds16(Ab + (size_t)(rowadd) * LDA + (kte) + ga0, lp + (bufb) + (halfb) + ld0); \
    gl_lds16(Ab + (size_t)(rowadd) * LDA + (kte) + ga1,                            \
             lp + (bufb) + (halfb) + ld0 + 8192);                                  \
  } while (0)
#define PV_STGB(halfb, rowadd, bufb, kte) \
  gl_lds16(Bb + (size_t)(rowadd) * LDB + (kte) + gb0, lp + (bufb) + 32768 + (halfb) + ld0)

  // prologue
  PV_STGB(0, 0, 0, 0);
  PV_STGA(0, 0, 0, 0);
  PV_STGA(16384, 128, 0, 0);
  PV_STGB(8192, 64, 0, 0);
  PV_STGB(0, 0, BUFB, 64);
  PV_STGA(0, 0, BUFB, 64);
  asm volatile("s_waitcnt vmcnt(3)" ::: "memory");
  barx();

  short8 af[4], bf0[4], bf1[4];
  for (int t = 0; t < NT; ++t) {
    const int cbo = (t & 1) * BUFB, nbo = cbo ^ BUFB;
    const int kt1 = ((t + 1) & (NT - 1)) * 64;
    const int kt2 = ((t + 2) & (NT - 1)) * 64;
    // ---- phase 1: A mh0 + B nh0, stage Ah1(t+1)
#pragma unroll
    for (int mt = 0; mt < 2; mt++) {
      af[2 * mt] = *(const short8*)(lp + cbo + arb + mt * 2048 + cst0);
      af[2 * mt + 1] = *(const short8*)(lp + cbo + arb + mt * 2048 + cst1);
    }
#pragma unroll
    for (int nt = 0; nt < 2; nt++) {
      bf0[2 * nt] = *(const short8*)(lp + cbo + brb + nt * 2048 + cst0);
      bf0[2 * nt + 1] = *(const short8*)(lp + cbo + brb + nt * 2048 + cst1);
    }
    PV_STGA(16384, 128, nbo, kt1);
    barx();
    __builtin_amdgcn_s_setprio(1);
#pragma unroll
    for (int mt = 0; mt < 2; mt++) {
#pragma unroll
      for (int nt = 0; nt < 2; nt++) {
        acc[mt][nt] = MFMA16(af[2 * mt], bf0[2 * nt], acc[mt][nt]);
        acc[mt][nt] = MFMA16(af[2 * mt + 1], bf0[2 * nt + 1], acc[mt][nt]);
      }
      if (ONES) {
        accl[mt] = MFMA16(af[2 * mt], ones, accl[mt]);
        accl[mt] = MFMA16(af[2 * mt + 1], ones, accl[mt]);
      }
    }
    __builtin_amdgcn_s_setprio(0);
    barx();
    // ---- phase 2: B nh1, stage Bh1(t+1)
#pragma unroll
    for (int nt = 0; nt < 2; nt++) {
      bf1[2 * nt] = *(const short8*)(lp + cbo + brb + (nt + 2) * 2048 + cst0);
      bf1[2 * nt + 1] = *(const short8*)(lp + cbo + brb + (nt + 2) * 2048 + cst1);
    }
    PV_STGB(8192, 64, nbo, kt1);
    barx();
    __builtin_amdgcn_s_setprio(1);
#pragma unroll
    for (int mt = 0; mt < 2; mt++)
#pragma unroll
      for (int nt = 0; nt < 2; nt++) {
        acc[mt][nt + 2] = MFMA16(af[2 * mt], bf1[2 * nt], acc[mt][nt + 2]);
        acc[mt][nt + 2] = MFMA16(af[2 * mt + 1], bf1[2 * nt + 1], acc[mt][nt + 2]);
      }
    __builtin_amdgcn_s_setprio(0);
    barx();
    // ---- phase 3: A mh1, stage Bh0(t+2)
#pragma unroll
    for (int mt = 0; mt < 2; mt++) {
      af[2 * mt] = *(const short8*)(lp + cbo + arb + (mt + 2) * 2048 + cst0);
      af[2 * mt + 1] = *(const short8*)(lp + cbo + arb + (mt + 2) * 2048 + cst1);
    }
    PV_STGB(0, 0, cbo, kt2);
    barx();
    __builtin_amdgcn_s_setprio(1);
#pragma unroll
    for (int mt = 0; mt < 2; mt++) {
#pragma unroll
      for (int nt = 0; nt < 2; nt++) {
        acc[mt + 2][nt + 2] = MFMA16(af[2 * mt], bf1[2 * nt], acc[mt + 2][nt + 2]);
        acc[mt + 2][nt + 2] = MFMA16(af[2 * mt + 1], bf1[2 * nt + 1], acc[mt + 2][nt + 2]);
      }
      if (ONES) {
        accl[mt + 2] = MFMA16(af[2 * mt], ones, accl[mt + 2]);
        accl[mt + 2] = MFMA16(af[2 * mt + 1], ones, accl[mt + 2]);
      }
    }
    __builtin_amdgcn_s_setprio(0);
    barx();
    // ---- phase 4: stage Ah0(t+2), counted vmcnt, MFMA mh1 x nh0 (bf0 kept)
    PV_STGA(0, 0, cbo, kt2);
    asm volatile("s_waitcnt vmcnt(3)" ::: "memory");
    barx();
    __builtin_amdgcn_s_setprio(1);
#pragma unroll
    for (int mt = 0; mt < 2; mt++)
#pragma unroll
      for (int nt = 0; nt < 2; nt++) {
        acc[mt + 2][nt] = MFMA16(af[2 * mt], bf0[2 * nt], acc[mt + 2][nt]);
        acc[mt + 2][nt] = MFMA16(af[2 * mt + 1], bf0[2 * nt + 1], acc[mt + 2][nt]);
      }
    __builtin_amdgcn_s_setprio(0);
    barx();
  }
#undef PV_STGA
#undef PV_STGB
}

// ---------------------------------------------------------------------------
// proj: Q/K = xbf @ Wbf^T (bf16). grid (64, 8, 2), block 512
// ---------------------------------------------------------------------------
__global__ __launch_bounds__(512) void proj_kernel(
    const unsigned short* __restrict__ xbf, const unsigned short* __restrict__ Wqb,
    const unsigned short* __restrict__ Wkb, unsigned short* __restrict__ Qo,
    unsigned short* __restrict__ Ko) {
  __shared__ __attribute__((aligned(16))) short lds[49152];  // 96 KiB
  const unsigned short* Wb = blockIdx.z ? Wkb : Wqb;
  unsigned short* O = blockIdx.z ? Ko : Qo;
  const int m0 = blockIdx.x * 256, e0 = blockIdx.y * 128;
  fx4 acc[4][4], accl[4];
  core128<0, 16, 1024, 1024>(xbf + (size_t)m0 * 1024, Wb + (size_t)e0 * 1024, lds, acc, accl);
  const int wave = threadIdx.x >> 6, lane = threadIdx.x & 63;
  const int wm = wave >> 1, wn = wave & 1;
  const int quad = lane >> 4, l16 = lane & 15;
#pragma unroll
  for (int mt = 0; mt < 4; mt++) {
    const int row = m0 + wm * 64 + mt * 16 + quad * 4;
#pragma unroll
    for (int nt = 0; nt < 4; nt++) {
      const int col = e0 + wn * 64 + nt * 16 + l16;
      unsigned short* op = O + (size_t)row * 1024 + col;
#pragma unroll
      for (int i = 0; i < 4; i++) op[(size_t)i * 1024] = f2bfu(acc[mt][nt][i]);
    }
  }
}

// ---------------------------------------------------------------------------
// pv: O[b][q][d] = (P[bz] @ xT[b]^T) / (P[bz] @ 1), bf16 out.
// grid (16, 8, 2), block 512, K=4096
// ---------------------------------------------------------------------------
__global__ __launch_bounds__(512) void pv_kernel(
    const unsigned short* __restrict__ P, const unsigned short* __restrict__ xT,
    unsigned short* __restrict__ Ost, int bbase) {
  __shared__ __attribute__((aligned(16))) short lds[49152];  // 96 KiB
  const int bz = blockIdx.z, b = bbase + bz;
  const int m0 = blockIdx.x * 256, e0 = blockIdx.y * 128;
  const unsigned short* Ab = P + (size_t)bz * 4096 * 4096 + (size_t)m0 * 4096;
  const unsigned short* Bb = xT + (size_t)b * 1024 * 4096 + (size_t)e0 * 4096;
  fx4 acc[4][4], accl[4];
  core128<1, 64, 4096, 4096>(Ab, Bb, lds, acc, accl);
  unsigned short* O = Ost + (size_t)b * 4096 * 1024;
  const int wave = threadIdx.x >> 6, lane = threadIdx.x & 63;
  const int wm = wave >> 1, wn = wave & 1;
  const int quad = lane >> 4, l16 = lane & 15;
#pragma unroll
  for (int mt = 0; mt < 4; mt++) {
    const int row = m0 + wm * 64 + mt * 16 + quad * 4;
    const fx4 li = accl[mt];
    fx4 r;
#pragma unroll
    for (int i = 0; i < 4; i++) r[i] = __builtin_amdgcn_rcpf(li[i]);
#pragma unroll
    for (int nt = 0; nt < 4; nt++) {
      const int col = e0 + wn * 64 + nt * 16 + l16;
      unsigned short* op = O + (size_t)row * 1024 + col;
#pragma unroll
      for (int i = 0; i < 4; i++) op[(size_t)i * 1024] = f2bfu(acc[mt][nt][i] * r[i]);
    }
  }
}

// ---------------------------------------------------------------------------
// qk: P[bz][q][key] = exp2((Q[b] @ K[b]^T) * SCL) bf16.
// grid (16, 16, 2), block 512, BM=BN=256, K=1024. 128 KiB LDS.
// waves 2M x 4N (wave tile 128 x 64), acc[8][4]. vmcnt steady state = 4.
// ---------------------------------------------------------------------------
__global__ __launch_bounds__(512) void qk_kernel(
    const unsigned short* __restrict__ Qb, const unsigned short* __restrict__ Kb,
    unsigned short* __restrict__ Pp, int bbase) {
  constexpr int NT = 16;
  __shared__ __attribute__((aligned(16))) short lds[65536];  // 128 KiB
  const int bz = blockIdx.z, b = bbase + bz;
  const unsigned short* A = Qb + (size_t)b * 4096 * 1024;
  const unsigned short* Bm = Kb + (size_t)b * 4096 * 1024;
  unsigned short* Pb = Pp + (size_t)bz * 4096 * 4096;
  const int m0 = blockIdx.x * 256, n0 = blockIdx.y * 256;
  const int tid = threadIdx.x;
  const int wave = tid >> 6, lane = tid & 63;
  const int wm = wave >> 2, wn = wave & 3;
  const int quad = lane >> 4, l16 = lane & 15;
  char* lp = (char*)lds;

  const unsigned short* Ab = A + (size_t)m0 * 1024;
  const unsigned short* Bb = Bm + (size_t)n0 * 1024;
  const int sr0 = tid >> 3, so0 = (tid & 7) ^ (sr0 & 7);
  const int ga0 = sr0 * 1024 + so0 * 8;
  const int ga1 = ga0 + 64 * 1024;
  const int ld0 = tid * 16;

  const int cst0 = (quad ^ (l16 & 7)) * 16;
  const int cst1 = ((4 + quad) ^ (l16 & 7)) * 16;
  const int arb = wm * 16384 + l16 * 128;
  const int brb = 32768 + (wn >> 1) * 16384 + (wn & 1) * 8192 + l16 * 128;

  fx4 acc[8][4];
#pragma unroll
  for (int i = 0; i < 8; i++)
#pragma unroll
    for (int j = 0; j < 4; j++) acc[i][j] = (fx4)0.f;

#define QK_STG(OPb, halfb, rowadd, bufb, kte)                                       \
  do {                                                                              \
    gl_lds16(OPb + (size_t)(rowadd) * 1024 + (kte) + ga0, lp + (bufb) + (halfb) + ld0); \
    gl_lds16(OPb + (size_t)(rowadd) * 1024 + (kte) + ga1,                           \
             lp + (bufb) + (halfb) + ld0 + 8192);                                   \
  } while (0)

  // prologue
  QK_STG(Bb, 32768, 0, 0, 0);
  QK_STG(Ab, 0, 0, 0, 0);
  QK_STG(Ab, 16384, 128, 0, 0);
  QK_STG(Bb, 49152, 128, 0, 0);
  QK_STG(Bb, 32768, 0, 65536, 64);
  QK_STG(Ab, 0, 0, 65536, 64);
  asm volatile("s_waitcnt vmcnt(4)" ::: "memory");
  barx();

  short8 af[8], bf0[4], bf1[4];
  for (int t = 0; t < NT; ++t) {
    const int cbo = (t & 1) * 65536, nbo = cbo ^ 65536;
    const int kt1 = ((t + 1) & (NT - 1)) * 64;
    const int kt2 = ((t + 2) & (NT - 1)) * 64;
    // ---- phase 1: A mh0 (mt 0..3) + B nh0 (nt 0..1), stage Ah1(t+1)
#pragma unroll
    for (int mt = 0; mt < 4; mt++) {
      af[2 * mt] = *(const short8*)(lp + cbo + arb + mt * 2048 + cst0);
      af[2 * mt + 1] = *(const short8*)(lp + cbo + arb + mt * 2048 + cst1);
    }
#pragma unroll
    for (int nt = 0; nt < 2; nt++) {
      bf0[2 * nt] = *(const short8*)(lp + cbo + brb + nt * 2048 + cst0);
      bf0[2 * nt + 1] = *(const short8*)(lp + cbo + brb + nt * 2048 + cst1);
    }
    QK_STG(Ab, 16384, 128, nbo, kt1);
    barx();
    __builtin_amdgcn_s_setprio(1);
#pragma unroll
    for (int mt = 0; mt < 4; mt++)
#pragma unroll
      for (int nt = 0; nt < 2; nt++) {
        acc[mt][nt] = MFMA16(af[2 * mt], bf0[2 * nt], acc[mt][nt]);
        acc[mt][nt] = MFMA16(af[2 * mt + 1], bf0[2 * nt + 1], acc[mt][nt]);
      }
    __builtin_amdgcn_s_setprio(0);
    barx();
    // ---- phase 2: B nh1 (nt 2..3), stage Bh1(t+1)
#pragma unroll
    for (int nt = 0; nt < 2; nt++) {
      bf1[2 * nt] = *(const short8*)(lp + cbo + brb + (nt + 2) * 2048 + cst0);
      bf1[2 * nt + 1] = *(const short8*)(lp + cbo + brb + (nt + 2) * 2048 + cst1);
    }
    QK_STG(Bb, 49152, 128, nbo, kt1);
    barx();
    __builtin_amdgcn_s_setprio(1);
#pragma unroll
    for (int mt = 0; mt < 4; mt++)
#pragma unroll
      for (int nt = 0; nt < 2; nt++) {
        acc[mt][nt + 2] = MFMA16(af[2 * mt], bf1[2 * nt], acc[mt][nt + 2]);
        acc[mt][nt + 2] = MFMA16(af[2 * mt + 1], bf1[2 * nt + 1], acc[mt][nt + 2]);
      }
    __builtin_amdgcn_s_setprio(0);
    barx();
    // ---- phase 3: A mh1 (mt 4..7), stage Bh0(t+2)
#pragma unroll
    for (int mt = 0; mt < 4; mt++) {
      af[2 * mt] = *(const short8*)(lp + cbo + arb + (mt + 4) * 2048 + cst0);
      af[2 * mt + 1] = *(const short8*)(lp + cbo + arb + (mt + 4) * 2048 + cst1);
    }
    QK_STG(Bb, 32768, 0, cbo, kt2);
    barx();
    __builtin_amdgcn_s_setprio(1);
#pragma unroll
    for (int mt = 0; mt < 4; mt++)
#pragma unroll
      for (int nt = 0; nt < 2; nt++) {
        acc[mt + 4][nt + 2] = MFMA16(af[2 * mt], bf1[2 * nt], acc[mt + 4][nt + 2]);
        acc[mt + 4][nt + 2] = MFMA16(af[2 * mt + 1], bf1[2 * nt + 1], acc[mt + 4][nt + 2]);
      }
    __builtin_amdgcn_s_setprio(0);
    barx();
    // ---- phase 4: stage Ah0(t+2), counted vmcnt, MFMA mh1 x nh0
    QK_STG(Ab, 0, 0, cbo, kt2);
    asm volatile("s_waitcnt vmcnt(4)" ::: "memory");
    barx();
    __builtin_amdgcn_s_setprio(1);
#pragma unroll
    for (int mt = 0; mt < 4; mt++)
#pragma unroll
      for (int nt = 0; nt < 2; nt++) {
        acc[mt + 4][nt] = MFMA16(af[2 * mt], bf0[2 * nt], acc[mt + 4][nt]);
        acc[mt + 4][nt] = MFMA16(af[2 * mt + 1], bf0[2 * nt + 1], acc[mt + 4][nt]);
      }
    __builtin_amdgcn_s_setprio(0);
    barx();
  }
#undef QK_STG
  // epilogue: exp2 + bf16 store
#pragma unroll
  for (int mt = 0; mt < 8; mt++) {
    const int row = m0 + wm * 128 + mt * 16 + quad * 4;
#pragma unroll
    for (int nt = 0; nt < 4; nt++) {
      const int col = n0 + wn * 64 + nt * 16 + l16;
      unsigned short* pp = Pb + (size_t)row * 4096 + col;
#pragma unroll
      for (int i = 0; i < 4; i++)
        pp[(size_t)i * 4096] = f2bfu(fast_exp2(acc[mt][nt][i] * SCL));
    }
  }
}

// ---------------------------------------------------------------------------
// fin: O bf16 [B,N,D] -> d_out fp32
// ---------------------------------------------------------------------------
__global__ __launch_bounds__(256) void fin_kernel(const uint4* __restrict__ Ost,
                                                  float4* __restrict__ out) {
  size_t t = (size_t)blockIdx.x * 256 + threadIdx.x;
  const uint4 v = Ost[t];
  float4 o0, o1;
  o0.x = __builtin_bit_cast(float, v.x << 16);
  o0.y = __builtin_bit_cast(float, v.x & 0xffff0000u);
  o0.z = __builtin_bit_cast(float, v.y << 16);
  o0.w = __builtin_bit_cast(float, v.y & 0xffff0000u);
  o1.x = __builtin_bit_cast(float, v.z << 16);
  o1.y = __builtin_bit_cast(float, v.z & 0xffff0000u);
  o1.z = __builtin_bit_cast(float, v.w << 16);
  o1.w = __builtin_bit_cast(float, v.w & 0xffff0000u);
  out[t * 2] = o0;
  out[t * 2 + 1] = o1;
}

// ---------------------------------------------------------------------------
extern "C" void kernel_launch(void* const* d_in, const int* in_sizes, int n_in,
                              void* d_out, int out_size, void* d_ws, size_t ws_size,
                              hipStream_t stream) {
  const float* x = (const float*)d_in[0];
  const float* Wq = (const float*)d_in[1];
  const float* Wk = (const float*)d_in[2];
  char* ws = (char*)d_ws;
  // ws (96 MiB): xT bf16 @0 | Q bf16 @32Mi | K bf16 @64Mi
  // Q region reused as bf16 O staging once Q[b] is dead.
  unsigned short* xT = (unsigned short*)ws;
  unsigned short* Qb = (unsigned short*)(ws + (size_t)33554432);
  unsigned short* Kb = (unsigned short*)(ws + (size_t)67108864);
  unsigned short* Ost = Qb;
  // d_out as scratch until fin: phase A xbf/Wqb/Wkb; phase B P pair (64 MiB).
  unsigned short* xbf = (unsigned short*)d_out;
  unsigned short* Wqb = (unsigned short*)((char*)d_out + (size_t)33554432);
  unsigned short* Wkb = (unsigned short*)((char*)d_out + (size_t)35651584);
  unsigned short* Pp = (unsigned short*)d_out;

  hipLaunchKernelGGL(prep_kernel, dim3(64, 16, 4), dim3(256), 0, stream, x, xT, xbf);
  hipLaunchKernelGGL(wconv_kernel, dim3(2048), dim3(256), 0, stream, Wq, Wk, Wqb, Wkb);
  hipLaunchKernelGGL(proj_kernel, dim3(64, 8, 2), dim3(512), 0, stream, xbf, Wqb, Wkb, Qb, Kb);
  hipLaunchKernelGGL(qk_kernel, dim3(16, 16, 2), dim3(512), 0, stream, Qb, Kb, Pp, 0);
  hipLaunchKernelGGL(pv_kernel, dim3(16, 8, 2), dim3(512), 0, stream, Pp, xT, Ost, 0);
  hipLaunchKernelGGL(qk_kernel, dim3(16, 16, 2), dim3(512), 0, stream, Qb, Kb, Pp, 2);
  hipLaunchKernelGGL(pv_kernel, dim3(16, 8, 2), dim3(512), 0, stream, Pp, xT, Ost, 2);
  hipLaunchKernelGGL(fin_kernel, dim3(8192), dim3(256), 0, stream,
                     (const uint4*)Ost, (float4*)d_out);
}

// Round 4
// 474.516 us; speedup vs baseline: 1.4452x; 1.0476x over previous
//
#include <hip/hip_runtime.h>
#include <stdint.h>
#include <math.h>

typedef __attribute__((ext_vector_type(8))) short short8;
typedef __attribute__((ext_vector_type(4))) float fx4;
typedef unsigned int u32;

#define MFMA16(a, b, c) __builtin_amdgcn_mfma_f32_16x16x32_bf16(a, b, c, 0, 0, 0)
#define SCL 0.04508422002777948f  // log2(e)/sqrt(1024)

#define CFENCE asm volatile("" ::: "memory")

// fp32 -> bf16 (RTNE), raw bits
__device__ __forceinline__ unsigned short f2bfu(float f) {
  unsigned u = __builtin_bit_cast(unsigned, f);
  u += 0x7fffu + ((u >> 16) & 1u);
  return (unsigned short)(u >> 16);
}

// raw v_exp_f32 (2^x), no ocml guard path
__device__ __forceinline__ float fast_exp2(float x) {
  float r;
  asm("v_exp_f32 %0, %1" : "=v"(r) : "v"(x));
  return r;
}

// async global->LDS, 16B per lane (dest = wave-uniform base + lane*16)
__device__ __forceinline__ void gl_lds16(const void* g, void* l) {
  __builtin_amdgcn_global_load_lds(
      (const __attribute__((address_space(1))) u32*)g,
      (__attribute__((address_space(3))) u32*)l, 16, 0, 0);
}

__device__ __forceinline__ void barx() {
  CFENCE;
  __builtin_amdgcn_s_barrier();
  CFENCE;
}

// ---------------------------------------------------------------------------
// prep: x [B,N,D] fp32 -> xbf [B,N,D] bf16 AND xT [B,D,N] bf16
// ---------------------------------------------------------------------------
__global__ __launch_bounds__(256) void prep_kernel(const float* __restrict__ x,
                                                   unsigned short* __restrict__ xT,
                                                   unsigned short* __restrict__ xbf) {
  __shared__ float tile[64 * 65];
  const int b = blockIdx.z, n0 = blockIdx.x * 64, d0 = blockIdx.y * 64;
  const int tid = threadIdx.x;
  const float* xb = x + ((size_t)b * 4096 + n0) * 1024 + d0;
#pragma unroll
  for (int i = 0; i < 4; i++) {
    int idx = tid + 256 * i;
    int r = idx >> 4, c4 = (idx & 15) * 4;
    const float4 v = *(const float4*)(xb + (size_t)r * 1024 + c4);
    float* tp = &tile[r * 65 + c4];
    tp[0] = v.x; tp[1] = v.y; tp[2] = v.z; tp[3] = v.w;
    uint2 pkt;
    pkt.x = (u32)f2bfu(v.x) | ((u32)f2bfu(v.y) << 16);
    pkt.y = (u32)f2bfu(v.z) | ((u32)f2bfu(v.w) << 16);
    *(uint2*)(xbf + ((size_t)b * 4096 + n0 + r) * 1024 + d0 + c4) = pkt;
  }
  __syncthreads();
  unsigned short* xo = xT + ((size_t)b * 1024 + d0) * 4096 + n0;
#pragma unroll
  for (int i = 0; i < 4; i++) {
    int idx = tid + 256 * i;
    int dr = idx >> 4, n4 = (idx & 15) * 4;
    unsigned short h0 = f2bfu(tile[(n4 + 0) * 65 + dr]);
    unsigned short h1 = f2bfu(tile[(n4 + 1) * 65 + dr]);
    unsigned short h2 = f2bfu(tile[(n4 + 2) * 65 + dr]);
    unsigned short h3 = f2bfu(tile[(n4 + 3) * 65 + dr]);
    uint2 pkt;
    pkt.x = (u32)h0 | ((u32)h1 << 16);
    pkt.y = (u32)h2 | ((u32)h3 << 16);
    *(uint2*)(xo + (size_t)dr * 4096 + n4) = pkt;
  }
}

// ---------------------------------------------------------------------------
// wconv: Wq,Wk fp32 [1024,1024] -> bf16
// ---------------------------------------------------------------------------
__global__ __launch_bounds__(256) void wconv_kernel(const float* __restrict__ Wq,
                                                    const float* __restrict__ Wk,
                                                    unsigned short* __restrict__ Wqb,
                                                    unsigned short* __restrict__ Wkb) {
  int gid = blockIdx.x * 256 + threadIdx.x;
  const float* s = (gid < 262144) ? Wq : Wk;
  unsigned short* d = (gid < 262144) ? Wqb : Wkb;
  int off = (gid & 262143) * 4;
  const float4 v = *(const float4*)(s + off);
  uint2 pkt;
  pkt.x = (u32)f2bfu(v.x) | ((u32)f2bfu(v.y) << 16);
  pkt.y = (u32)f2bfu(v.z) | ((u32)f2bfu(v.w) << 16);
  *(uint2*)(d + off) = pkt;
}

// ===========================================================================
// core256: BM=BN=256, K=1024 (NT=16), BK=64, 512 threads (8 waves, 2M x 4N,
// wave tile 128x64, acc[8][4]). 128 KiB LDS. 4 phases/K-tile, 16 MFMA/phase.
// LDS per half-tile: [128 rows][64 shorts]; slot s: row=s>>3, oct=(s&7)^(row&7),
// byte = halfbase + s*16 (linear, global_load_lds). Read (rel row ra, step st,
// quad q): byte = ra*128 + (((st*4+q)^(ra&7))*16).
// Stage plan per tile t: P1 Ah1(t+1)->nbuf, P2 Bh1(t+1)->nbuf,
// P3 Bh0(t+2)->cbuf, P4 Ah0(t+2)->cbuf + vmcnt(4). Proven (r1/r3).
// ===========================================================================
__device__ __forceinline__ void core256(const unsigned short* __restrict__ Ab,
                                        const unsigned short* __restrict__ Bb,
                                        char* lp, fx4 (&acc)[8][4]) {
  constexpr int NT = 16;
  const int tid = threadIdx.x;
  const int wave = tid >> 6, lane = tid & 63;
  const int wm = wave >> 2, wn = wave & 3;
  const int quad = lane >> 4, l16 = lane & 15;

  const int sr0 = tid >> 3, so0 = (tid & 7) ^ (sr0 & 7);
  const int ga0 = sr0 * 1024 + so0 * 8;
  const int ga1 = ga0 + 64 * 1024;
  const int ld0 = tid * 16;

  const int cst0 = (quad ^ (l16 & 7)) * 16;
  const int cst1 = ((4 + quad) ^ (l16 & 7)) * 16;
  const int arb = wm * 16384 + l16 * 128;
  const int brb = 32768 + (wn >> 1) * 16384 + (wn & 1) * 8192 + l16 * 128;

#pragma unroll
  for (int i = 0; i < 8; i++)
#pragma unroll
    for (int j = 0; j < 4; j++) acc[i][j] = (fx4)0.f;

#define C_STG(OPb, halfb, rowadd, bufb, kte)                                        \
  do {                                                                              \
    gl_lds16(OPb + (size_t)(rowadd) * 1024 + (kte) + ga0, lp + (bufb) + (halfb) + ld0); \
    gl_lds16(OPb + (size_t)(rowadd) * 1024 + (kte) + ga1,                           \
             lp + (bufb) + (halfb) + ld0 + 8192);                                   \
  } while (0)

  // prologue
  C_STG(Bb, 32768, 0, 0, 0);
  C_STG(Ab, 0, 0, 0, 0);
  C_STG(Ab, 16384, 128, 0, 0);
  C_STG(Bb, 49152, 128, 0, 0);
  C_STG(Bb, 32768, 0, 65536, 64);
  C_STG(Ab, 0, 0, 65536, 64);
  asm volatile("s_waitcnt vmcnt(4)" ::: "memory");
  barx();

  short8 af[8], bf0[4], bf1[4];
  for (int t = 0; t < NT; ++t) {
    const int cbo = (t & 1) * 65536, nbo = cbo ^ 65536;
    const int kt1 = ((t + 1) & (NT - 1)) * 64;
    const int kt2 = ((t + 2) & (NT - 1)) * 64;
    // ---- phase 1: A mh0 (mt 0..3) + B nh0 (nt 0..1), stage Ah1(t+1)
#pragma unroll
    for (int mt = 0; mt < 4; mt++) {
      af[2 * mt] = *(const short8*)(lp + cbo + arb + mt * 2048 + cst0);
      af[2 * mt + 1] = *(const short8*)(lp + cbo + arb + mt * 2048 + cst1);
    }
#pragma unroll
    for (int nt = 0; nt < 2; nt++) {
      bf0[2 * nt] = *(const short8*)(lp + cbo + brb + nt * 2048 + cst0);
      bf0[2 * nt + 1] = *(const short8*)(lp + cbo + brb + nt * 2048 + cst1);
    }
    C_STG(Ab, 16384, 128, nbo, kt1);
    barx();
    __builtin_amdgcn_s_setprio(1);
#pragma unroll
    for (int mt = 0; mt < 4; mt++)
#pragma unroll
      for (int nt = 0; nt < 2; nt++) {
        acc[mt][nt] = MFMA16(af[2 * mt], bf0[2 * nt], acc[mt][nt]);
        acc[mt][nt] = MFMA16(af[2 * mt + 1], bf0[2 * nt + 1], acc[mt][nt]);
      }
    __builtin_amdgcn_s_setprio(0);
    barx();
    // ---- phase 2: B nh1 (nt 2..3), stage Bh1(t+1)
#pragma unroll
    for (int nt = 0; nt < 2; nt++) {
      bf1[2 * nt] = *(const short8*)(lp + cbo + brb + (nt + 2) * 2048 + cst0);
      bf1[2 * nt + 1] = *(const short8*)(lp + cbo + brb + (nt + 2) * 2048 + cst1);
    }
    C_STG(Bb, 49152, 128, nbo, kt1);
    barx();
    __builtin_amdgcn_s_setprio(1);
#pragma unroll
    for (int mt = 0; mt < 4; mt++)
#pragma unroll
      for (int nt = 0; nt < 2; nt++) {
        acc[mt][nt + 2] = MFMA16(af[2 * mt], bf1[2 * nt], acc[mt][nt + 2]);
        acc[mt][nt + 2] = MFMA16(af[2 * mt + 1], bf1[2 * nt + 1], acc[mt][nt + 2]);
      }
    __builtin_amdgcn_s_setprio(0);
    barx();
    // ---- phase 3: A mh1 (mt 4..7), stage Bh0(t+2)
#pragma unroll
    for (int mt = 0; mt < 4; mt++) {
      af[2 * mt] = *(const short8*)(lp + cbo + arb + (mt + 4) * 2048 + cst0);
      af[2 * mt + 1] = *(const short8*)(lp + cbo + arb + (mt + 4) * 2048 + cst1);
    }
    C_STG(Bb, 32768, 0, cbo, kt2);
    barx();
    __builtin_amdgcn_s_setprio(1);
#pragma unroll
    for (int mt = 0; mt < 4; mt++)
#pragma unroll
      for (int nt = 0; nt < 2; nt++) {
        acc[mt + 4][nt + 2] = MFMA16(af[2 * mt], bf1[2 * nt], acc[mt + 4][nt + 2]);
        acc[mt + 4][nt + 2] = MFMA16(af[2 * mt + 1], bf1[2 * nt + 1], acc[mt + 4][nt + 2]);
      }
    __builtin_amdgcn_s_setprio(0);
    barx();
    // ---- phase 4: stage Ah0(t+2), counted vmcnt, MFMA mh1 x nh0
    C_STG(Ab, 0, 0, cbo, kt2);
    asm volatile("s_waitcnt vmcnt(4)" ::: "memory");
    barx();
    __builtin_amdgcn_s_setprio(1);
#pragma unroll
    for (int mt = 0; mt < 4; mt++)
#pragma unroll
      for (int nt = 0; nt < 2; nt++) {
        acc[mt + 4][nt] = MFMA16(af[2 * mt], bf0[2 * nt], acc[mt + 4][nt]);
        acc[mt + 4][nt] = MFMA16(af[2 * mt + 1], bf0[2 * nt + 1], acc[mt + 4][nt]);
      }
    __builtin_amdgcn_s_setprio(0);
    barx();
  }
#undef C_STG
}

// ---------------------------------------------------------------------------
// proj: Q/K = xbf @ Wbf^T (bf16). grid (64, 4, 2), block 512, 256x256 tile
// ---------------------------------------------------------------------------
__global__ __launch_bounds__(512) void proj_kernel(
    const unsigned short* __restrict__ xbf, const unsigned short* __restrict__ Wqb,
    const unsigned short* __restrict__ Wkb, unsigned short* __restrict__ Qo,
    unsigned short* __restrict__ Ko) {
  __shared__ __attribute__((aligned(16))) short lds[65536];  // 128 KiB
  const unsigned short* Wb = blockIdx.z ? Wkb : Wqb;
  unsigned short* O = blockIdx.z ? Ko : Qo;
  const int m0 = blockIdx.x * 256, e0 = blockIdx.y * 256;
  fx4 acc[8][4];
  core256(xbf + (size_t)m0 * 1024, Wb + (size_t)e0 * 1024, (char*)lds, acc);
  const int wave = threadIdx.x >> 6, lane = threadIdx.x & 63;
  const int wm = wave >> 2, wn = wave & 3;
  const int quad = lane >> 4, l16 = lane & 15;
#pragma unroll
  for (int mt = 0; mt < 8; mt++) {
    const int row = m0 + wm * 128 + mt * 16 + quad * 4;
#pragma unroll
    for (int nt = 0; nt < 4; nt++) {
      const int col = e0 + wn * 64 + nt * 16 + l16;
      unsigned short* op = O + (size_t)row * 1024 + col;
#pragma unroll
      for (int i = 0; i < 4; i++) op[(size_t)i * 1024] = f2bfu(acc[mt][nt][i]);
    }
  }
}

// ---------------------------------------------------------------------------
// qk: P[bz][q][key] = exp2((Q[b] @ K[b]^T) * SCL) bf16. grid (16, 16, 2)
// ---------------------------------------------------------------------------
__global__ __launch_bounds__(512) void qk_kernel(
    const unsigned short* __restrict__ Qb, const unsigned short* __restrict__ Kb,
    unsigned short* __restrict__ Pp, int bbase) {
  __shared__ __attribute__((aligned(16))) short lds[65536];  // 128 KiB
  const int bz = blockIdx.z, b = bbase + bz;
  unsigned short* Pb = Pp + (size_t)bz * 4096 * 4096;
  const int m0 = blockIdx.x * 256, n0 = blockIdx.y * 256;
  fx4 acc[8][4];
  core256(Qb + (size_t)b * 4096 * 1024 + (size_t)m0 * 1024,
          Kb + (size_t)b * 4096 * 1024 + (size_t)n0 * 1024, (char*)lds, acc);
  const int wave = threadIdx.x >> 6, lane = threadIdx.x & 63;
  const int wm = wave >> 2, wn = wave & 3;
  const int quad = lane >> 4, l16 = lane & 15;
#pragma unroll
  for (int mt = 0; mt < 8; mt++) {
    const int row = m0 + wm * 128 + mt * 16 + quad * 4;
#pragma unroll
    for (int nt = 0; nt < 4; nt++) {
      const int col = n0 + wn * 64 + nt * 16 + l16;
      unsigned short* pp = Pb + (size_t)row * 4096 + col;
#pragma unroll
      for (int i = 0; i < 4; i++)
        pp[(size_t)i * 4096] = f2bfu(fast_exp2(acc[mt][nt][i] * SCL));
    }
  }
}

// ---------------------------------------------------------------------------
// pv: O[b][q][d] = (P[bz] @ xT[b]^T) / (P[bz] @ 1), bf16 out.
// grid (16, 8, 2), block 512, K=4096 (NT=64), BM=256 BN=128.
// 2-phase schedule: per K-tile t (buffers alternate t&1):
//   P1: read A(all) + B nh0; stage Bh1(t+1)->nbuf [1]; vmcnt(5); bar;
//       MFMA m x nh0 (+ones rowsum); bar.
//   P2: read B nh1; stage A(t+2)+Bh0(t+2)->cbuf [5]; vmcnt(6); bar;
//       MFMA m x nh1; bar.
// WAR: Bh1(t+1) slot last read at t-1 P2 (2 barriers earlier); A/Bh0(t+2)
// slots last read at t P1 (2 barriers earlier). RAW: vmcnt(5) at P1 retires
// t-1 P1's Bh1(t) stage (oldest) before P2 reads it; vmcnt(6) at P2 retires
// t-1 P2's A/Bh0(t+1) batch before t+1 P1 reads it. Never drains to 0.
// ---------------------------------------------------------------------------
__global__ __launch_bounds__(512) void pv_kernel(
    const unsigned short* __restrict__ P, const unsigned short* __restrict__ xT,
    unsigned short* __restrict__ Ost, int bbase) {
  constexpr int NT = 64, BUFB = 49152;
  __shared__ __attribute__((aligned(16))) short lds[49152];  // 96 KiB
  const int bz = blockIdx.z, b = bbase + bz;
  const int m0 = blockIdx.x * 256, e0 = blockIdx.y * 128;
  const unsigned short* Ab = P + (size_t)bz * 4096 * 4096 + (size_t)m0 * 4096;
  const unsigned short* Bb = xT + (size_t)b * 1024 * 4096 + (size_t)e0 * 4096;
  const int tid = threadIdx.x;
  const int wave = tid >> 6, lane = tid & 63;
  const int wm = wave >> 1, wn = wave & 1;
  const int quad = lane >> 4, l16 = lane & 15;
  char* lp = (char*)lds;

  const int sr0 = tid >> 3, so0 = (tid & 7) ^ (sr0 & 7);
  const int g0 = sr0 * 4096 + so0 * 8;
  const int g1 = g0 + 64 * 4096;
  const int ld0 = tid * 16;

  const int cst0 = (quad ^ (l16 & 7)) * 16;
  const int cst1 = ((4 + quad) ^ (l16 & 7)) * 16;
  const int arb = (wm >> 1) * 16384 + (wm & 1) * 8192 + l16 * 128;
  const int brb = 32768 + wn * 8192 + l16 * 128;

  short8 ones;
#pragma unroll
  for (int i = 0; i < 8; i++) ones[i] = (short)0x3F80;  // bf16 1.0

  fx4 acc[4][4], accl[4];
#pragma unroll
  for (int i = 0; i < 4; i++) {
    accl[i] = (fx4)0.f;
#pragma unroll
    for (int j = 0; j < 4; j++) acc[i][j] = (fx4)0.f;
  }

#define PV_STGA(bufb, kte)                                                   \
  do {                                                                       \
    gl_lds16(Ab + (size_t)(kte) + g0, lp + (bufb) + ld0);                    \
    gl_lds16(Ab + (size_t)(kte) + g1, lp + (bufb) + ld0 + 8192);             \
    gl_lds16(Ab + (size_t)128 * 4096 + (kte) + g0, lp + (bufb) + 16384 + ld0); \
    gl_lds16(Ab + (size_t)128 * 4096 + (kte) + g1,                           \
             lp + (bufb) + 16384 + ld0 + 8192);                              \
  } while (0)
#define PV_STGB0(bufb, kte) gl_lds16(Bb + (size_t)(kte) + g0, lp + (bufb) + 32768 + ld0)
#define PV_STGB1(bufb, kte) \
  gl_lds16(Bb + (size_t)64 * 4096 + (kte) + g0, lp + (bufb) + 40960 + ld0)

  // prologue: tile0 full [6], tile1 A+B0 [5]; retire tile0 (11-5=6 oldest)
  PV_STGA(0, 0);
  PV_STGB0(0, 0);
  PV_STGB1(0, 0);
  PV_STGA(BUFB, 64);
  PV_STGB0(BUFB, 64);
  asm volatile("s_waitcnt vmcnt(5)" ::: "memory");
  barx();

  short8 af[8], bfv[4];
  for (int t = 0; t < NT; ++t) {
    const int cbo = (t & 1) * BUFB, nbo = cbo ^ BUFB;
    const int kt1 = ((t + 1) & (NT - 1)) * 64;
    const int kt2 = ((t + 2) & (NT - 1)) * 64;
    // ---- phase 1: all A (mt 0..3) + B nh0, stage Bh1(t+1)
#pragma unroll
    for (int mt = 0; mt < 4; mt++) {
      af[2 * mt] = *(const short8*)(lp + cbo + arb + mt * 2048 + cst0);
      af[2 * mt + 1] = *(const short8*)(lp + cbo + arb + mt * 2048 + cst1);
    }
#pragma unroll
    for (int nt = 0; nt < 2; nt++) {
      bfv[2 * nt] = *(const short8*)(lp + cbo + brb + nt * 2048 + cst0);
      bfv[2 * nt + 1] = *(const short8*)(lp + cbo + brb + nt * 2048 + cst1);
    }
    PV_STGB1(nbo, kt1);
    asm volatile("s_waitcnt vmcnt(5)" ::: "memory");
    barx();
    __builtin_amdgcn_s_setprio(1);
#pragma unroll
    for (int mt = 0; mt < 4; mt++) {
#pragma unroll
      for (int nt = 0; nt < 2; nt++) {
        acc[mt][nt] = MFMA16(af[2 * mt], bfv[2 * nt], acc[mt][nt]);
        acc[mt][nt] = MFMA16(af[2 * mt + 1], bfv[2 * nt + 1], acc[mt][nt]);
      }
      accl[mt] = MFMA16(af[2 * mt], ones, accl[mt]);
      accl[mt] = MFMA16(af[2 * mt + 1], ones, accl[mt]);
    }
    __builtin_amdgcn_s_setprio(0);
    barx();
    // ---- phase 2: B nh1, stage A(t+2)+Bh0(t+2) into cbuf
#pragma unroll
    for (int nt = 0; nt < 2; nt++) {
      bfv[2 * nt] = *(const short8*)(lp + cbo + brb + (nt + 2) * 2048 + cst0);
      bfv[2 * nt + 1] = *(const short8*)(lp + cbo + brb + (nt + 2) * 2048 + cst1);
    }
    PV_STGA(cbo, kt2);
    PV_STGB0(cbo, kt2);
    asm volatile("s_waitcnt vmcnt(6)" ::: "memory");
    barx();
    __builtin_amdgcn_s_setprio(1);
#pragma unroll
    for (int mt = 0; mt < 4; mt++)
#pragma unroll
      for (int nt = 0; nt < 2; nt++) {
        acc[mt][nt + 2] = MFMA16(af[2 * mt], bfv[2 * nt], acc[mt][nt + 2]);
        acc[mt][nt + 2] = MFMA16(af[2 * mt + 1], bfv[2 * nt + 1], acc[mt][nt + 2]);
      }
    __builtin_amdgcn_s_setprio(0);
    barx();
  }
#undef PV_STGA
#undef PV_STGB0
#undef PV_STGB1

  unsigned short* O = Ost + (size_t)b * 4096 * 1024;
#pragma unroll
  for (int mt = 0; mt < 4; mt++) {
    const int row = m0 + wm * 64 + mt * 16 + quad * 4;
    const fx4 li = accl[mt];
    fx4 r;
#pragma unroll
    for (int i = 0; i < 4; i++) r[i] = __builtin_amdgcn_rcpf(li[i]);
#pragma unroll
    for (int nt = 0; nt < 4; nt++) {
      const int col = e0 + wn * 64 + nt * 16 + l16;
      unsigned short* op = O + (size_t)row * 1024 + col;
#pragma unroll
      for (int i = 0; i < 4; i++) op[(size_t)i * 1024] = f2bfu(acc[mt][nt][i] * r[i]);
    }
  }
}

// ---------------------------------------------------------------------------
// fin: O bf16 [B,N,D] -> d_out fp32
// ---------------------------------------------------------------------------
__global__ __launch_bounds__(256) void fin_kernel(const uint4* __restrict__ Ost,
                                                  float4* __restrict__ out) {
  size_t t = (size_t)blockIdx.x * 256 + threadIdx.x;
  const uint4 v = Ost[t];
  float4 o0, o1;
  o0.x = __builtin_bit_cast(float, v.x << 16);
  o0.y = __builtin_bit_cast(float, v.x & 0xffff0000u);
  o0.z = __builtin_bit_cast(float, v.y << 16);
  o0.w = __builtin_bit_cast(float, v.y & 0xffff0000u);
  o1.x = __builtin_bit_cast(float, v.z << 16);
  o1.y = __builtin_bit_cast(float, v.z & 0xffff0000u);
  o1.z = __builtin_bit_cast(float, v.w << 16);
  o1.w = __builtin_bit_cast(float, v.w & 0xffff0000u);
  out[t * 2] = o0;
  out[t * 2 + 1] = o1;
}

// ---------------------------------------------------------------------------
extern "C" void kernel_launch(void* const* d_in, const int* in_sizes, int n_in,
                              void* d_out, int out_size, void* d_ws, size_t ws_size,
                              hipStream_t stream) {
  const float* x = (const float*)d_in[0];
  const float* Wq = (const float*)d_in[1];
  const float* Wk = (const float*)d_in[2];
  char* ws = (char*)d_ws;
  // ws (96 MiB): xT bf16 @0 | Q bf16 @32Mi | K bf16 @64Mi
  // Q region reused as bf16 O staging once Q[b] is dead.
  unsigned short* xT = (unsigned short*)ws;
  unsigned short* Qb = (unsigned short*)(ws + (size_t)33554432);
  unsigned short* Kb = (unsigned short*)(ws + (size_t)67108864);
  unsigned short* Ost = Qb;
  // d_out as scratch until fin: phase A xbf/Wqb/Wkb; phase B P pair (64 MiB).
  unsigned short* xbf = (unsigned short*)d_out;
  unsigned short* Wqb = (unsigned short*)((char*)d_out + (size_t)33554432);
  unsigned short* Wkb = (unsigned short*)((char*)d_out + (size_t)35651584);
  unsigned short* Pp = (unsigned short*)d_out;

  hipLaunchKernelGGL(prep_kernel, dim3(64, 16, 4), dim3(256), 0, stream, x, xT, xbf);
  hipLaunchKernelGGL(wconv_kernel, dim3(2048), dim3(256), 0, stream, Wq, Wk, Wqb, Wkb);
  hipLaunchKernelGGL(proj_kernel, dim3(64, 4, 2), dim3(512), 0, stream, xbf, Wqb, Wkb, Qb, Kb);
  hipLaunchKernelGGL(qk_kernel, dim3(16, 16, 2), dim3(512), 0, stream, Qb, Kb, Pp, 0);
  hipLaunchKernelGGL(pv_kernel, dim3(16, 8, 2), dim3(512), 0, stream, Pp, xT, Ost, 0);
  hipLaunchKernelGGL(qk_kernel, dim3(16, 16, 2), dim3(512), 0, stream, Qb, Kb, Pp, 2);
  hipLaunchKernelGGL(pv_kernel, dim3(16, 8, 2), dim3(512), 0, stream, Pp, xT, Ost, 2);
  hipLaunchKernelGGL(fin_kernel, dim3(8192), dim3(256), 0, stream,
                     (const uint4*)Ost, (float4*)d_out);
}

// Round 5
// 468.576 us; speedup vs baseline: 1.4635x; 1.0127x over previous
//
#include <hip/hip_runtime.h>
#include <stdint.h>
#include <math.h>

typedef __attribute__((ext_vector_type(8))) short short8;
typedef __attribute__((ext_vector_type(4))) float fx4;
typedef unsigned int u32;

#define MFMA16(a, b, c) __builtin_amdgcn_mfma_f32_16x16x32_bf16(a, b, c, 0, 0, 0)
#define SCL 0.04508422002777948f  // log2(e)/sqrt(1024)

#define CFENCE asm volatile("" ::: "memory")

// fp32 -> bf16 (RTNE), raw bits
__device__ __forceinline__ unsigned short f2bfu(float f) {
  unsigned u = __builtin_bit_cast(unsigned, f);
  u += 0x7fffu + ((u >> 16) & 1u);
  return (unsigned short)(u >> 16);
}

// raw v_exp_f32 (2^x), no ocml guard path
__device__ __forceinline__ float fast_exp2(float x) {
  float r;
  asm("v_exp_f32 %0, %1" : "=v"(r) : "v"(x));
  return r;
}

// async global->LDS, 16B per lane (dest = wave-uniform base + lane*16)
__device__ __forceinline__ void gl_lds16(const void* g, void* l) {
  __builtin_amdgcn_global_load_lds(
      (const __attribute__((address_space(1))) u32*)g,
      (__attribute__((address_space(3))) u32*)l, 16, 0, 0);
}

__device__ __forceinline__ void barx() {
  CFENCE;
  __builtin_amdgcn_s_barrier();
  CFENCE;
}

// ---------------------------------------------------------------------------
// prep: x [B,N,D] fp32 -> xbf [B,N,D] bf16 AND xT [B,D,N] bf16
// ---------------------------------------------------------------------------
__global__ __launch_bounds__(256) void prep_kernel(const float* __restrict__ x,
                                                   unsigned short* __restrict__ xT,
                                                   unsigned short* __restrict__ xbf) {
  __shared__ float tile[64 * 65];
  const int b = blockIdx.z, n0 = blockIdx.x * 64, d0 = blockIdx.y * 64;
  const int tid = threadIdx.x;
  const float* xb = x + ((size_t)b * 4096 + n0) * 1024 + d0;
#pragma unroll
  for (int i = 0; i < 4; i++) {
    int idx = tid + 256 * i;
    int r = idx >> 4, c4 = (idx & 15) * 4;
    const float4 v = *(const float4*)(xb + (size_t)r * 1024 + c4);
    float* tp = &tile[r * 65 + c4];
    tp[0] = v.x; tp[1] = v.y; tp[2] = v.z; tp[3] = v.w;
    uint2 pkt;
    pkt.x = (u32)f2bfu(v.x) | ((u32)f2bfu(v.y) << 16);
    pkt.y = (u32)f2bfu(v.z) | ((u32)f2bfu(v.w) << 16);
    *(uint2*)(xbf + ((size_t)b * 4096 + n0 + r) * 1024 + d0 + c4) = pkt;
  }
  __syncthreads();
  unsigned short* xo = xT + ((size_t)b * 1024 + d0) * 4096 + n0;
#pragma unroll
  for (int i = 0; i < 4; i++) {
    int idx = tid + 256 * i;
    int dr = idx >> 4, n4 = (idx & 15) * 4;
    unsigned short h0 = f2bfu(tile[(n4 + 0) * 65 + dr]);
    unsigned short h1 = f2bfu(tile[(n4 + 1) * 65 + dr]);
    unsigned short h2 = f2bfu(tile[(n4 + 2) * 65 + dr]);
    unsigned short h3 = f2bfu(tile[(n4 + 3) * 65 + dr]);
    uint2 pkt;
    pkt.x = (u32)h0 | ((u32)h1 << 16);
    pkt.y = (u32)h2 | ((u32)h3 << 16);
    *(uint2*)(xo + (size_t)dr * 4096 + n4) = pkt;
  }
}

// ---------------------------------------------------------------------------
// wconv: Wq,Wk fp32 [1024,1024] -> bf16
// ---------------------------------------------------------------------------
__global__ __launch_bounds__(256) void wconv_kernel(const float* __restrict__ Wq,
                                                    const float* __restrict__ Wk,
                                                    unsigned short* __restrict__ Wqb,
                                                    unsigned short* __restrict__ Wkb) {
  int gid = blockIdx.x * 256 + threadIdx.x;
  const float* s = (gid < 262144) ? Wq : Wk;
  unsigned short* d = (gid < 262144) ? Wqb : Wkb;
  int off = (gid & 262143) * 4;
  const float4 v = *(const float4*)(s + off);
  uint2 pkt;
  pkt.x = (u32)f2bfu(v.x) | ((u32)f2bfu(v.y) << 16);
  pkt.y = (u32)f2bfu(v.z) | ((u32)f2bfu(v.w) << 16);
  *(uint2*)(d + off) = pkt;
}

// ===========================================================================
// core256: BM=BN=256, K=1024 (NT=16), BK=64, 512 threads (8 waves, 2M x 4N,
// wave tile 128x64, acc[8][4]). 128 KiB LDS. 4 phases/K-tile, 16 MFMA/phase.
// LDS per half-tile: [128 rows][64 shorts]; slot s: row=s>>3, oct=(s&7)^(row&7),
// byte = halfbase + s*16 (linear, global_load_lds). Read (rel row ra, step st,
// quad q): byte = ra*128 + (((st*4+q)^(ra&7))*16).
// Stage plan per tile t: P1 Ah1(t+1)->nbuf, P2 Bh1(t+1)->nbuf,
// P3 Bh0(t+2)->cbuf, P4 Ah0(t+2)->cbuf + vmcnt(4). Proven (r1/r3/r4).
// ===========================================================================
__device__ __forceinline__ void core256(const unsigned short* __restrict__ Ab,
                                        const unsigned short* __restrict__ Bb,
                                        char* lp, fx4 (&acc)[8][4]) {
  constexpr int NT = 16;
  const int tid = threadIdx.x;
  const int wave = tid >> 6, lane = tid & 63;
  const int wm = wave >> 2, wn = wave & 3;
  const int quad = lane >> 4, l16 = lane & 15;

  const int sr0 = tid >> 3, so0 = (tid & 7) ^ (sr0 & 7);
  const int ga0 = sr0 * 1024 + so0 * 8;
  const int ga1 = ga0 + 64 * 1024;
  const int ld0 = tid * 16;

  const int cst0 = (quad ^ (l16 & 7)) * 16;
  const int cst1 = ((4 + quad) ^ (l16 & 7)) * 16;
  const int arb = wm * 16384 + l16 * 128;
  const int brb = 32768 + (wn >> 1) * 16384 + (wn & 1) * 8192 + l16 * 128;

#pragma unroll
  for (int i = 0; i < 8; i++)
#pragma unroll
    for (int j = 0; j < 4; j++) acc[i][j] = (fx4)0.f;

#define C_STG(OPb, halfb, rowadd, bufb, kte)                                        \
  do {                                                                              \
    gl_lds16(OPb + (size_t)(rowadd) * 1024 + (kte) + ga0, lp + (bufb) + (halfb) + ld0); \
    gl_lds16(OPb + (size_t)(rowadd) * 1024 + (kte) + ga1,                           \
             lp + (bufb) + (halfb) + ld0 + 8192);                                   \
  } while (0)

  // prologue
  C_STG(Bb, 32768, 0, 0, 0);
  C_STG(Ab, 0, 0, 0, 0);
  C_STG(Ab, 16384, 128, 0, 0);
  C_STG(Bb, 49152, 128, 0, 0);
  C_STG(Bb, 32768, 0, 65536, 64);
  C_STG(Ab, 0, 0, 65536, 64);
  asm volatile("s_waitcnt vmcnt(4)" ::: "memory");
  barx();

  short8 af[8], bf0[4], bf1[4];
  for (int t = 0; t < NT; ++t) {
    const int cbo = (t & 1) * 65536, nbo = cbo ^ 65536;
    const int kt1 = ((t + 1) & (NT - 1)) * 64;
    const int kt2 = ((t + 2) & (NT - 1)) * 64;
    // ---- phase 1: A mh0 (mt 0..3) + B nh0 (nt 0..1), stage Ah1(t+1)
#pragma unroll
    for (int mt = 0; mt < 4; mt++) {
      af[2 * mt] = *(const short8*)(lp + cbo + arb + mt * 2048 + cst0);
      af[2 * mt + 1] = *(const short8*)(lp + cbo + arb + mt * 2048 + cst1);
    }
#pragma unroll
    for (int nt = 0; nt < 2; nt++) {
      bf0[2 * nt] = *(const short8*)(lp + cbo + brb + nt * 2048 + cst0);
      bf0[2 * nt + 1] = *(const short8*)(lp + cbo + brb + nt * 2048 + cst1);
    }
    C_STG(Ab, 16384, 128, nbo, kt1);
    barx();
    __builtin_amdgcn_s_setprio(1);
#pragma unroll
    for (int mt = 0; mt < 4; mt++)
#pragma unroll
      for (int nt = 0; nt < 2; nt++) {
        acc[mt][nt] = MFMA16(af[2 * mt], bf0[2 * nt], acc[mt][nt]);
        acc[mt][nt] = MFMA16(af[2 * mt + 1], bf0[2 * nt + 1], acc[mt][nt]);
      }
    __builtin_amdgcn_s_setprio(0);
    barx();
    // ---- phase 2: B nh1 (nt 2..3), stage Bh1(t+1)
#pragma unroll
    for (int nt = 0; nt < 2; nt++) {
      bf1[2 * nt] = *(const short8*)(lp + cbo + brb + (nt + 2) * 2048 + cst0);
      bf1[2 * nt + 1] = *(const short8*)(lp + cbo + brb + (nt + 2) * 2048 + cst1);
    }
    C_STG(Bb, 49152, 128, nbo, kt1);
    barx();
    __builtin_amdgcn_s_setprio(1);
#pragma unroll
    for (int mt = 0; mt < 4; mt++)
#pragma unroll
      for (int nt = 0; nt < 2; nt++) {
        acc[mt][nt + 2] = MFMA16(af[2 * mt], bf1[2 * nt], acc[mt][nt + 2]);
        acc[mt][nt + 2] = MFMA16(af[2 * mt + 1], bf1[2 * nt + 1], acc[mt][nt + 2]);
      }
    __builtin_amdgcn_s_setprio(0);
    barx();
    // ---- phase 3: A mh1 (mt 4..7), stage Bh0(t+2)
#pragma unroll
    for (int mt = 0; mt < 4; mt++) {
      af[2 * mt] = *(const short8*)(lp + cbo + arb + (mt + 4) * 2048 + cst0);
      af[2 * mt + 1] = *(const short8*)(lp + cbo + arb + (mt + 4) * 2048 + cst1);
    }
    C_STG(Bb, 32768, 0, cbo, kt2);
    barx();
    __builtin_amdgcn_s_setprio(1);
#pragma unroll
    for (int mt = 0; mt < 4; mt++)
#pragma unroll
      for (int nt = 0; nt < 2; nt++) {
        acc[mt + 4][nt + 2] = MFMA16(af[2 * mt], bf1[2 * nt], acc[mt + 4][nt + 2]);
        acc[mt + 4][nt + 2] = MFMA16(af[2 * mt + 1], bf1[2 * nt + 1], acc[mt + 4][nt + 2]);
      }
    __builtin_amdgcn_s_setprio(0);
    barx();
    // ---- phase 4: stage Ah0(t+2), counted vmcnt, MFMA mh1 x nh0
    C_STG(Ab, 0, 0, cbo, kt2);
    asm volatile("s_waitcnt vmcnt(4)" ::: "memory");
    barx();
    __builtin_amdgcn_s_setprio(1);
#pragma unroll
    for (int mt = 0; mt < 4; mt++)
#pragma unroll
      for (int nt = 0; nt < 2; nt++) {
        acc[mt + 4][nt] = MFMA16(af[2 * mt], bf0[2 * nt], acc[mt + 4][nt]);
        acc[mt + 4][nt] = MFMA16(af[2 * mt + 1], bf0[2 * nt + 1], acc[mt + 4][nt]);
      }
    __builtin_amdgcn_s_setprio(0);
    barx();
  }
#undef C_STG
}

// ===========================================================================
// core128: BM=256, BN=128, BK=64, 512 threads (8 waves, 4M x 2N, wave tile
// 64x64, acc[4][4]). 96 KiB LDS. 8-phase, 8 MFMA/phase (+2 ones in P1/P3).
// Stage plan per tile t: P1 Ah1(t+1)->nbuf, P2 Bh1(t+1)->nbuf,
// P3 Bh0(t+2)->cbuf, P4 Ah0(t+2)->cbuf + vmcnt(3). Proven (r1/r3).
// ===========================================================================
template <int ONES, int NT, int LDA, int LDB>
__device__ __forceinline__ void core128(const unsigned short* __restrict__ Ab,
                                        const unsigned short* __restrict__ Bb,
                                        short* lds, fx4 (&acc)[4][4], fx4 (&accl)[4]) {
  constexpr int BUFB = 49152;  // bytes per buffer: A 32K + B 16K
  const int tid = threadIdx.x;
  const int wave = tid >> 6, lane = tid & 63;
  const int wm = wave >> 1, wn = wave & 1;
  const int quad = lane >> 4, l16 = lane & 15;
  char* lp = (char*)lds;

  const int sr0 = tid >> 3, so0 = (tid & 7) ^ (sr0 & 7);
  const int ga0 = sr0 * LDA + so0 * 8;
  const int ga1 = ga0 + 64 * LDA;
  const int gb0 = sr0 * LDB + so0 * 8;
  const int ld0 = tid * 16;

  const int cst0 = (quad ^ (l16 & 7)) * 16;
  const int cst1 = ((4 + quad) ^ (l16 & 7)) * 16;
  const int arb = (wm >> 1) * 16384 + (wm & 1) * 8192 + l16 * 128;
  const int brb = 32768 + wn * 8192 + l16 * 128;

  short8 ones;
#pragma unroll
  for (int i = 0; i < 8; i++) ones[i] = (short)0x3F80;
#pragma unroll
  for (int i = 0; i < 4; i++) {
    accl[i] = (fx4)0.f;
#pragma unroll
    for (int j = 0; j < 4; j++) acc[i][j] = (fx4)0.f;
  }

#define PV_STGA(halfb, rowadd, bufb, kte)                                          \
  do {                                                                             \
    gl_lds16(Ab + (size_t)(rowadd) * LDA + (kte) + ga0, lp + (bufb) + (halfb) + ld0); \
    gl_lds16(Ab + (size_t)(rowadd) * LDA + (kte) + ga1,                            \
             lp + (bufb) + (halfb) + ld0 + 8192);                                  \
  } while (0)
#define PV_STGB(halfb, rowadd, bufb, kte) \
  gl_lds16(Bb + (size_t)(rowadd) * LDB + (kte) + gb0, lp + (bufb) + 32768 + (halfb) + ld0)

  // prologue
  PV_STGB(0, 0, 0, 0);
  PV_STGA(0, 0, 0, 0);
  PV_STGA(16384, 128, 0, 0);
  PV_STGB(8192, 64, 0, 0);
  PV_STGB(0, 0, BUFB, 64);
  PV_STGA(0, 0, BUFB, 64);
  asm volatile("s_waitcnt vmcnt(3)" ::: "memory");
  barx();

  short8 af[4], bf0[4], bf1[4];
  for (int t = 0; t < NT; ++t) {
    const int cbo = (t & 1) * BUFB, nbo = cbo ^ BUFB;
    const int kt1 = ((t + 1) & (NT - 1)) * 64;
    const int kt2 = ((t + 2) & (NT - 1)) * 64;
    // ---- phase 1: A mh0 + B nh0, stage Ah1(t+1)
#pragma unroll
    for (int mt = 0; mt < 2; mt++) {
      af[2 * mt] = *(const short8*)(lp + cbo + arb + mt * 2048 + cst0);
      af[2 * mt + 1] = *(const short8*)(lp + cbo + arb + mt * 2048 + cst1);
    }
#pragma unroll
    for (int nt = 0; nt < 2; nt++) {
      bf0[2 * nt] = *(const short8*)(lp + cbo + brb + nt * 2048 + cst0);
      bf0[2 * nt + 1] = *(const short8*)(lp + cbo + brb + nt * 2048 + cst1);
    }
    PV_STGA(16384, 128, nbo, kt1);
    barx();
    __builtin_amdgcn_s_setprio(1);
#pragma unroll
    for (int mt = 0; mt < 2; mt++) {
#pragma unroll
      for (int nt = 0; nt < 2; nt++) {
        acc[mt][nt] = MFMA16(af[2 * mt], bf0[2 * nt], acc[mt][nt]);
        acc[mt][nt] = MFMA16(af[2 * mt + 1], bf0[2 * nt + 1], acc[mt][nt]);
      }
      if (ONES) {
        accl[mt] = MFMA16(af[2 * mt], ones, accl[mt]);
        accl[mt] = MFMA16(af[2 * mt + 1], ones, accl[mt]);
      }
    }
    __builtin_amdgcn_s_setprio(0);
    barx();
    // ---- phase 2: B nh1, stage Bh1(t+1)
#pragma unroll
    for (int nt = 0; nt < 2; nt++) {
      bf1[2 * nt] = *(const short8*)(lp + cbo + brb + (nt + 2) * 2048 + cst0);
      bf1[2 * nt + 1] = *(const short8*)(lp + cbo + brb + (nt + 2) * 2048 + cst1);
    }
    PV_STGB(8192, 64, nbo, kt1);
    barx();
    __builtin_amdgcn_s_setprio(1);
#pragma unroll
    for (int mt = 0; mt < 2; mt++)
#pragma unroll
      for (int nt = 0; nt < 2; nt++) {
        acc[mt][nt + 2] = MFMA16(af[2 * mt], bf1[2 * nt], acc[mt][nt + 2]);
        acc[mt][nt + 2] = MFMA16(af[2 * mt + 1], bf1[2 * nt + 1], acc[mt][nt + 2]);
      }
    __builtin_amdgcn_s_setprio(0);
    barx();
    // ---- phase 3: A mh1, stage Bh0(t+2)
#pragma unroll
    for (int mt = 0; mt < 2; mt++) {
      af[2 * mt] = *(const short8*)(lp + cbo + arb + (mt + 2) * 2048 + cst0);
      af[2 * mt + 1] = *(const short8*)(lp + cbo + arb + (mt + 2) * 2048 + cst1);
    }
    PV_STGB(0, 0, cbo, kt2);
    barx();
    __builtin_amdgcn_s_setprio(1);
#pragma unroll
    for (int mt = 0; mt < 2; mt++) {
#pragma unroll
      for (int nt = 0; nt < 2; nt++) {
        acc[mt + 2][nt + 2] = MFMA16(af[2 * mt], bf1[2 * nt], acc[mt + 2][nt + 2]);
        acc[mt + 2][nt + 2] = MFMA16(af[2 * mt + 1], bf1[2 * nt + 1], acc[mt + 2][nt + 2]);
      }
      if (ONES) {
        accl[mt + 2] = MFMA16(af[2 * mt], ones, accl[mt + 2]);
        accl[mt + 2] = MFMA16(af[2 * mt + 1], ones, accl[mt + 2]);
      }
    }
    __builtin_amdgcn_s_setprio(0);
    barx();
    // ---- phase 4: stage Ah0(t+2), counted vmcnt, MFMA mh1 x nh0 (bf0 kept)
    PV_STGA(0, 0, cbo, kt2);
    asm volatile("s_waitcnt vmcnt(3)" ::: "memory");
    barx();
    __builtin_amdgcn_s_setprio(1);
#pragma unroll
    for (int mt = 0; mt < 2; mt++)
#pragma unroll
      for (int nt = 0; nt < 2; nt++) {
        acc[mt + 2][nt] = MFMA16(af[2 * mt], bf0[2 * nt], acc[mt + 2][nt]);
        acc[mt + 2][nt] = MFMA16(af[2 * mt + 1], bf0[2 * nt + 1], acc[mt + 2][nt]);
      }
    __builtin_amdgcn_s_setprio(0);
    barx();
  }
#undef PV_STGA
#undef PV_STGB
}

// ---------------------------------------------------------------------------
// proj: Q/K = xbf @ Wbf^T (bf16). grid (64, 4, 2), block 512, 256x256 tile
// ---------------------------------------------------------------------------
__global__ __launch_bounds__(512) void proj_kernel(
    const unsigned short* __restrict__ xbf, const unsigned short* __restrict__ Wqb,
    const unsigned short* __restrict__ Wkb, unsigned short* __restrict__ Qo,
    unsigned short* __restrict__ Ko) {
  __shared__ __attribute__((aligned(16))) short lds[65536];  // 128 KiB
  const unsigned short* Wb = blockIdx.z ? Wkb : Wqb;
  unsigned short* O = blockIdx.z ? Ko : Qo;
  const int m0 = blockIdx.x * 256, e0 = blockIdx.y * 256;
  fx4 acc[8][4];
  core256(xbf + (size_t)m0 * 1024, Wb + (size_t)e0 * 1024, (char*)lds, acc);
  const int wave = threadIdx.x >> 6, lane = threadIdx.x & 63;
  const int wm = wave >> 2, wn = wave & 3;
  const int quad = lane >> 4, l16 = lane & 15;
#pragma unroll
  for (int mt = 0; mt < 8; mt++) {
    const int row = m0 + wm * 128 + mt * 16 + quad * 4;
#pragma unroll
    for (int nt = 0; nt < 4; nt++) {
      const int col = e0 + wn * 64 + nt * 16 + l16;
      unsigned short* op = O + (size_t)row * 1024 + col;
#pragma unroll
      for (int i = 0; i < 4; i++) op[(size_t)i * 1024] = f2bfu(acc[mt][nt][i]);
    }
  }
}

// ---------------------------------------------------------------------------
// qk: P[bz][q][key] = exp2((Q[b] @ K[b]^T) * SCL) bf16. grid (16, 16, 2),
// XCD-swizzled (nwg=512, bijective): hw-blocks on one XCD compute 64
// consecutive tiles = 4 full K-panels -> K-panel L2-resident per XCD.
// ---------------------------------------------------------------------------
__global__ __launch_bounds__(512) void qk_kernel(
    const unsigned short* __restrict__ Qb, const unsigned short* __restrict__ Kb,
    unsigned short* __restrict__ Pp, int bbase) {
  __shared__ __attribute__((aligned(16))) short lds[65536];  // 128 KiB
  const int fid = blockIdx.x + 16 * blockIdx.y + 256 * blockIdx.z;  // nwg=512
  const int swz = (fid & 7) * 64 + (fid >> 3);
  const int bx = swz & 15, by = (swz >> 4) & 15, bz = swz >> 8;
  const int b = bbase + bz;
  unsigned short* Pb = Pp + (size_t)bz * 4096 * 4096;
  const int m0 = bx * 256, n0 = by * 256;
  fx4 acc[8][4];
  core256(Qb + (size_t)b * 4096 * 1024 + (size_t)m0 * 1024,
          Kb + (size_t)b * 4096 * 1024 + (size_t)n0 * 1024, (char*)lds, acc);
  const int wave = threadIdx.x >> 6, lane = threadIdx.x & 63;
  const int wm = wave >> 2, wn = wave & 3;
  const int quad = lane >> 4, l16 = lane & 15;
#pragma unroll
  for (int mt = 0; mt < 8; mt++) {
    const int row = m0 + wm * 128 + mt * 16 + quad * 4;
#pragma unroll
    for (int nt = 0; nt < 4; nt++) {
      const int col = n0 + wn * 64 + nt * 16 + l16;
      unsigned short* pp = Pb + (size_t)row * 4096 + col;
#pragma unroll
      for (int i = 0; i < 4; i++)
        pp[(size_t)i * 4096] = f2bfu(fast_exp2(acc[mt][nt][i] * SCL));
    }
  }
}

// ---------------------------------------------------------------------------
// pv: O[b][q][d] = (P[bz] @ xT[b]^T) / (P[bz] @ 1), bf16 out.
// grid (16, 8, 2), block 512, K=4096, 4-phase core128 (proven), XCD-swizzled
// (nwg=256): 32 consecutive tiles/XCD = 2 full xT-panels L2-resident.
// ---------------------------------------------------------------------------
__global__ __launch_bounds__(512) void pv_kernel(
    const unsigned short* __restrict__ P, const unsigned short* __restrict__ xT,
    unsigned short* __restrict__ Ost, int bbase) {
  __shared__ __attribute__((aligned(16))) short lds[49152];  // 96 KiB
  const int fid = blockIdx.x + 16 * blockIdx.y + 128 * blockIdx.z;  // nwg=256
  const int swz = (fid & 7) * 32 + (fid >> 3);
  const int bx = swz & 15, by = (swz >> 4) & 7, bz = swz >> 7;
  const int b = bbase + bz;
  const int m0 = bx * 256, e0 = by * 128;
  const unsigned short* Ab = P + (size_t)bz * 4096 * 4096 + (size_t)m0 * 4096;
  const unsigned short* Bb = xT + (size_t)b * 1024 * 4096 + (size_t)e0 * 4096;
  fx4 acc[4][4], accl[4];
  core128<1, 64, 4096, 4096>(Ab, Bb, lds, acc, accl);
  unsigned short* O = Ost + (size_t)b * 4096 * 1024;
  const int wave = threadIdx.x >> 6, lane = threadIdx.x & 63;
  const int wm = wave >> 1, wn = wave & 1;
  const int quad = lane >> 4, l16 = lane & 15;
#pragma unroll
  for (int mt = 0; mt < 4; mt++) {
    const int row = m0 + wm * 64 + mt * 16 + quad * 4;
    const fx4 li = accl[mt];
    fx4 r;
#pragma unroll
    for (int i = 0; i < 4; i++) r[i] = __builtin_amdgcn_rcpf(li[i]);
#pragma unroll
    for (int nt = 0; nt < 4; nt++) {
      const int col = e0 + wn * 64 + nt * 16 + l16;
      unsigned short* op = O + (size_t)row * 1024 + col;
#pragma unroll
      for (int i = 0; i < 4; i++) op[(size_t)i * 1024] = f2bfu(acc[mt][nt][i] * r[i]);
    }
  }
}

// ---------------------------------------------------------------------------
// fin: O bf16 [B,N,D] -> d_out fp32
// ---------------------------------------------------------------------------
__global__ __launch_bounds__(256) void fin_kernel(const uint4* __restrict__ Ost,
                                                  float4* __restrict__ out) {
  size_t t = (size_t)blockIdx.x * 256 + threadIdx.x;
  const uint4 v = Ost[t];
  float4 o0, o1;
  o0.x = __builtin_bit_cast(float, v.x << 16);
  o0.y = __builtin_bit_cast(float, v.x & 0xffff0000u);
  o0.z = __builtin_bit_cast(float, v.y << 16);
  o0.w = __builtin_bit_cast(float, v.y & 0xffff0000u);
  o1.x = __builtin_bit_cast(float, v.z << 16);
  o1.y = __builtin_bit_cast(float, v.z & 0xffff0000u);
  o1.z = __builtin_bit_cast(float, v.w << 16);
  o1.w = __builtin_bit_cast(float, v.w & 0xffff0000u);
  out[t * 2] = o0;
  out[t * 2 + 1] = o1;
}

// ---------------------------------------------------------------------------
extern "C" void kernel_launch(void* const* d_in, const int* in_sizes, int n_in,
                              void* d_out, int out_size, void* d_ws, size_t ws_size,
                              hipStream_t stream) {
  const float* x = (const float*)d_in[0];
  const float* Wq = (const float*)d_in[1];
  const float* Wk = (const float*)d_in[2];
  char* ws = (char*)d_ws;
  // ws (96 MiB): xT bf16 @0 | Q bf16 @32Mi | K bf16 @64Mi
  // Q region reused as bf16 O staging once Q[b] is dead.
  unsigned short* xT = (unsigned short*)ws;
  unsigned short* Qb = (unsigned short*)(ws + (size_t)33554432);
  unsigned short* Kb = (unsigned short*)(ws + (size_t)67108864);
  unsigned short* Ost = Qb;
  // d_out as scratch until fin: phase A xbf/Wqb/Wkb; phase B P pair (64 MiB).
  unsigned short* xbf = (unsigned short*)d_out;
  unsigned short* Wqb = (unsigned short*)((char*)d_out + (size_t)33554432);
  unsigned short* Wkb = (unsigned short*)((char*)d_out + (size_t)35651584);
  unsigned short* Pp = (unsigned short*)d_out;

  hipLaunchKernelGGL(prep_kernel, dim3(64, 16, 4), dim3(256), 0, stream, x, xT, xbf);
  hipLaunchKernelGGL(wconv_kernel, dim3(2048), dim3(256), 0, stream, Wq, Wk, Wqb, Wkb);
  hipLaunchKernelGGL(proj_kernel, dim3(64, 4, 2), dim3(512), 0, stream, xbf, Wqb, Wkb, Qb, Kb);
  hipLaunchKernelGGL(qk_kernel, dim3(16, 16, 2), dim3(512), 0, stream, Qb, Kb, Pp, 0);
  hipLaunchKernelGGL(pv_kernel, dim3(16, 8, 2), dim3(512), 0, stream, Pp, xT, Ost, 0);
  hipLaunchKernelGGL(qk_kernel, dim3(16, 16, 2), dim3(512), 0, stream, Qb, Kb, Pp, 2);
  hipLaunchKernelGGL(pv_kernel, dim3(16, 8, 2), dim3(512), 0, stream, Pp, xT, Ost, 2);
  hipLaunchKernelGGL(fin_kernel, dim3(8192), dim3(256), 0, stream,
                     (const uint4*)Ost, (float4*)d_out);
}